// Round 1
// baseline (8267.432 us; speedup 1.0000x reference)
//
#include <hip/hip_runtime.h>

#define NN 100000
#define NE 1600000
#define D 64
#define NL 5
#define NG 1024
#define EMBD 320
#define BN_EPS 1e-5f

// ---------------- counts[g] = #nodes in graph g ----------------
__global__ __launch_bounds__(256) void k_counts(const int* __restrict__ batch,
                                                float* __restrict__ counts) {
  int i = blockIdx.x * 256 + threadIdx.x;
  if (i < NN) unsafeAtomicAdd(&counts[batch[i]], 1.0f);
}

// ---------------- msg[dst] += w * h[src]  (16 threads/edge, float4 each) ----
__global__ __launch_bounds__(256) void k_scatter(const float* __restrict__ h,
                                                 const int* __restrict__ src,
                                                 const int* __restrict__ dst,
                                                 const float* __restrict__ w,
                                                 float* __restrict__ msg) {
  int t = blockIdx.x * 256 + threadIdx.x;
  int e = t >> 4, p = t & 15;
  if (e >= NE) return;
  int s = src[e], d = dst[e];
  float we = w[e];
  float4 v = ((const float4*)(h + (size_t)s * D))[p];
  float* mp = msg + (size_t)d * D + p * 4;
  unsafeAtomicAdd(mp + 0, v.x * we);
  unsafeAtomicAdd(mp + 1, v.y * we);
  unsafeAtomicAdd(mp + 2, v.z * we);
  unsafeAtomicAdd(mp + 3, v.w * we);
}

// ---------------- h_next = relu(relu((h+msg)@W1+b1)@W2+b2), in-place over msg
__global__ __launch_bounds__(256) void k_gin(const float* __restrict__ h,
                                             float* mh,  // msg in, h_next out
                                             const float* __restrict__ W1,
                                             const float* __restrict__ b1,
                                             const float* __restrict__ W2,
                                             const float* __restrict__ b2) {
  __shared__ float sW1[D * D];
  __shared__ float sW2[D * D];
  __shared__ float sb1[D], sb2[D];
  for (int i = threadIdx.x; i < D * D; i += 256) { sW1[i] = W1[i]; sW2[i] = W2[i]; }
  if (threadIdx.x < D) { sb1[threadIdx.x] = b1[threadIdx.x]; sb2[threadIdx.x] = b2[threadIdx.x]; }
  __syncthreads();
  int node = blockIdx.x * 256 + threadIdx.x;
  if (node >= NN) return;
  const float4* hp = (const float4*)(h + (size_t)node * D);
  const float4* mp = (const float4*)(mh + (size_t)node * D);
  float v[D];
#pragma unroll
  for (int i = 0; i < D / 4; ++i) {
    float4 a = hp[i];
    float4 b = mp[i];
    v[4 * i + 0] = a.x + b.x;
    v[4 * i + 1] = a.y + b.y;
    v[4 * i + 2] = a.z + b.z;
    v[4 * i + 3] = a.w + b.w;
  }
  float tt[D];
#pragma unroll
  for (int j = 0; j < D; j += 4) {
    float a0 = sb1[j + 0], a1 = sb1[j + 1], a2 = sb1[j + 2], a3 = sb1[j + 3];
#pragma unroll
    for (int k = 0; k < D; ++k) {
      float vk = v[k];
      a0 = fmaf(vk, sW1[k * D + j + 0], a0);
      a1 = fmaf(vk, sW1[k * D + j + 1], a1);
      a2 = fmaf(vk, sW1[k * D + j + 2], a2);
      a3 = fmaf(vk, sW1[k * D + j + 3], a3);
    }
    tt[j + 0] = fmaxf(a0, 0.f);
    tt[j + 1] = fmaxf(a1, 0.f);
    tt[j + 2] = fmaxf(a2, 0.f);
    tt[j + 3] = fmaxf(a3, 0.f);
  }
  float4* op = (float4*)(mh + (size_t)node * D);
#pragma unroll
  for (int j = 0; j < D; j += 4) {
    float a0 = sb2[j + 0], a1 = sb2[j + 1], a2 = sb2[j + 2], a3 = sb2[j + 3];
#pragma unroll
    for (int k = 0; k < D; ++k) {
      float tk = tt[k];
      a0 = fmaf(tk, sW2[k * D + j + 0], a0);
      a1 = fmaf(tk, sW2[k * D + j + 1], a1);
      a2 = fmaf(tk, sW2[k * D + j + 2], a2);
      a3 = fmaf(tk, sW2[k * D + j + 3], a3);
    }
    float4 o;
    o.x = fmaxf(a0, 0.f);
    o.y = fmaxf(a1, 0.f);
    o.z = fmaxf(a2, 0.f);
    o.w = fmaxf(a3, 0.f);
    op[j >> 2] = o;
  }
}

// ---------------- per-feature sum / sumsq over nodes ----------------
__global__ __launch_bounds__(256) void k_bnstats(const float* __restrict__ h,
                                                 float* __restrict__ stats) {
  __shared__ float ss[256];
  __shared__ float sq[256];
  int f = threadIdx.x & (D - 1);
  int sub = threadIdx.x >> 6;  // 0..3
  float s = 0.f, q = 0.f;
  for (int n = blockIdx.x * 4 + sub; n < NN; n += gridDim.x * 4) {
    float x = h[(size_t)n * D + f];
    s += x;
    q += x * x;
  }
  ss[threadIdx.x] = s;
  sq[threadIdx.x] = q;
  __syncthreads();
  if (threadIdx.x < D) {
    s = ss[threadIdx.x] + ss[threadIdx.x + 64] + ss[threadIdx.x + 128] + ss[threadIdx.x + 192];
    q = sq[threadIdx.x] + sq[threadIdx.x + 64] + sq[threadIdx.x + 128] + sq[threadIdx.x + 192];
    unsafeAtomicAdd(&stats[f], s);
    unsafeAtomicAdd(&stats[D + f], q);
  }
}

// stats[128..191] = scale, stats[192..255] = shift
__global__ void k_bnfin(float* stats, const float* __restrict__ gamma,
                        const float* __restrict__ beta) {
  int f = threadIdx.x;  // 64 threads
  float mean = stats[f] * (1.0f / NN);
  float var = stats[D + f] * (1.0f / NN) - mean * mean;
  var = fmaxf(var, 0.f);
  float sc = gamma[f] * rsqrtf(var + BN_EPS);
  stats[2 * D + f] = sc;
  stats[3 * D + f] = beta[f] - mean * sc;
}

// ---------------- apply BN, write h_cur, accumulate pooled ----------------
__global__ __launch_bounds__(256) void k_bnapply(const float* __restrict__ hin,
                                                 const float* __restrict__ stats,
                                                 const int* __restrict__ batch,
                                                 float* __restrict__ hout,
                                                 float* __restrict__ pooled,
                                                 int layer) {
  int gid = blockIdx.x * 256 + threadIdx.x;
  if (gid >= NN * 16) return;
  int n = gid >> 4, p = gid & 15;
  float4 x = ((const float4*)(hin + (size_t)n * D))[p];
  float4 sc = ((const float4*)(stats + 2 * D))[p];
  float4 sh = ((const float4*)(stats + 3 * D))[p];
  float4 o;
  o.x = fmaf(x.x, sc.x, sh.x);
  o.y = fmaf(x.y, sc.y, sh.y);
  o.z = fmaf(x.z, sc.z, sh.z);
  o.w = fmaf(x.w, sc.w, sh.w);
  ((float4*)(hout + (size_t)n * D))[p] = o;
  int g = batch[n];
  float* pp = pooled + (size_t)g * EMBD + layer * D + p * 4;
  unsafeAtomicAdd(pp + 0, o.x);
  unsafeAtomicAdd(pp + 1, o.y);
  unsafeAtomicAdd(pp + 2, o.z);
  unsafeAtomicAdd(pp + 3, o.w);
}

// ---------------- projection head: one block (320 thr) per graph ----------
__global__ __launch_bounds__(EMBD) void k_proj(const float* __restrict__ pooled,
                                               const float* __restrict__ counts,
                                               const float* __restrict__ pW1,
                                               const float* __restrict__ pb1,
                                               const float* __restrict__ pW2,
                                               const float* __restrict__ pb2,
                                               float* __restrict__ out) {
  __shared__ float row[EMBD];
  __shared__ float y1[EMBD];
  int g = blockIdx.x, j = threadIdx.x;
  float cnt = fmaxf(counts[g], 1.0f);
  row[j] = pooled[(size_t)g * EMBD + j] / cnt;
  __syncthreads();
  float acc = pb1[j];
#pragma unroll 4
  for (int k = 0; k < EMBD; ++k) acc = fmaf(row[k], pW1[(size_t)k * EMBD + j], acc);
  y1[j] = fmaxf(acc, 0.f);
  __syncthreads();
  acc = pb2[j];
#pragma unroll 4
  for (int k = 0; k < EMBD; ++k) acc = fmaf(y1[k], pW2[(size_t)k * EMBD + j], acc);
  out[(size_t)g * EMBD + j] = acc;
}

extern "C" void kernel_launch(void* const* d_in, const int* in_sizes, int n_in,
                              void* d_out, int out_size, void* d_ws, size_t ws_size,
                              hipStream_t stream) {
  const float* x = (const float*)d_in[0];
  const int* ei = (const int*)d_in[1];
  const float* ew = (const float*)d_in[2];
  const int* batch = (const int*)d_in[3];
  const float* W1s = (const float*)d_in[4];
  const float* b1s = (const float*)d_in[5];
  const float* W2s = (const float*)d_in[6];
  const float* b2s = (const float*)d_in[7];
  const float* gammas = (const float*)d_in[8];
  const float* betas = (const float*)d_in[9];
  const float* pW1 = (const float*)d_in[10];
  const float* pb1 = (const float*)d_in[11];
  const float* pW2 = (const float*)d_in[12];
  const float* pb2 = (const float*)d_in[13];
  const int* srcv = ei;
  const int* dstv = ei + NE;

  float* ws = (float*)d_ws;
  float* msg = ws;                               // NN*D  (also h_next, in-place)
  float* hcur = msg + (size_t)NN * D;            // NN*D
  float* stats = hcur + (size_t)NN * D;          // 256
  float* pooled = stats + 256;                   // NG*EMBD
  float* counts = pooled + (size_t)NG * EMBD;    // NG

  // zero pooled + counts (contiguous)
  hipMemsetAsync(pooled, 0, ((size_t)NG * EMBD + NG) * sizeof(float), stream);
  k_counts<<<(NN + 255) / 256, 256, 0, stream>>>(batch, counts);

  const float* hin = x;
  for (int L = 0; L < NL; ++L) {
    hipMemsetAsync(msg, 0, (size_t)NN * D * sizeof(float), stream);
    hipMemsetAsync(stats, 0, 256 * sizeof(float), stream);
    k_scatter<<<(NE * 16 + 255) / 256, 256, 0, stream>>>(hin, srcv, dstv, ew, msg);
    k_gin<<<(NN + 255) / 256, 256, 0, stream>>>(hin, msg, W1s + L * D * D, b1s + L * D,
                                                W2s + L * D * D, b2s + L * D);
    k_bnstats<<<512, 256, 0, stream>>>(msg, stats);
    k_bnfin<<<1, 64, 0, stream>>>(stats, gammas + L * D, betas + L * D);
    k_bnapply<<<(NN * 16 + 255) / 256, 256, 0, stream>>>(msg, stats, batch, hcur, pooled, L);
    hin = hcur;
  }
  k_proj<<<NG, EMBD, 0, stream>>>(pooled, counts, pW1, pb1, pW2, pb2, (float*)d_out);
}

// Round 2
// 2257.904 us; speedup vs baseline: 3.6616x; 3.6616x over previous
//
#include <hip/hip_runtime.h>

#define NN 100000
#define NE 1600000
#define D 64
#define NL 5
#define NG 1024
#define EMBD 320
#define BN_EPS 1e-5f

// ---------------- counts[g] = #nodes in graph g ----------------
__global__ __launch_bounds__(256) void k_counts(const int* __restrict__ batch,
                                                float* __restrict__ counts) {
  int i = blockIdx.x * 256 + threadIdx.x;
  if (i < NN) unsafeAtomicAdd(&counts[batch[i]], 1.0f);
}

// ---------------- CSR build: histogram of dst ----------------
__global__ __launch_bounds__(256) void k_hist(const int* __restrict__ dst,
                                              int* __restrict__ deg) {
  int e = blockIdx.x * 256 + threadIdx.x;
  if (e < NE) atomicAdd(&deg[dst[e]], 1);
}

// ---------------- exclusive scan of deg (in row_ptr), single block --------
// row_ptr doubles as deg on input; also writes cursor = row_ptr.
__global__ __launch_bounds__(1024) void k_scan(int* __restrict__ row_ptr,
                                               int* __restrict__ cursor) {
  __shared__ int sums[1024];
  const int per = (NN + 1023) / 1024;  // 98
  int t = threadIdx.x;
  int base = t * per;
  int s = 0;
  for (int i = 0; i < per; ++i) {
    int idx = base + i;
    if (idx < NN) s += row_ptr[idx];
  }
  sums[t] = s;
  __syncthreads();
  // Hillis-Steele inclusive scan
  for (int off = 1; off < 1024; off <<= 1) {
    int u = (t >= off) ? sums[t - off] : 0;
    __syncthreads();
    sums[t] += u;
    __syncthreads();
  }
  int run = sums[t] - s;  // exclusive start for this thread's range
  for (int i = 0; i < per; ++i) {
    int idx = base + i;
    if (idx < NN) {
      int d = row_ptr[idx];
      row_ptr[idx] = run;
      cursor[idx] = run;
      run += d;
    }
  }
  if (t == 1023) row_ptr[NN] = sums[1023];
}

// ---------------- fill CSR (src, weight) ----------------
__global__ __launch_bounds__(256) void k_fill(const int* __restrict__ src,
                                              const int* __restrict__ dst,
                                              const float* __restrict__ w,
                                              int* __restrict__ cursor,
                                              int* __restrict__ esrc,
                                              float* __restrict__ ewt) {
  int e = blockIdx.x * 256 + threadIdx.x;
  if (e >= NE) return;
  int slot = atomicAdd(&cursor[dst[e]], 1);
  esrc[slot] = src[e];
  ewt[slot] = w[e];
}

// ---------------- msg[n] = sum_{e in row n} w_e * h[src_e]  (16 thr/node) --
__global__ __launch_bounds__(256) void k_gather(const float* __restrict__ h,
                                                const int* __restrict__ row_ptr,
                                                const int* __restrict__ esrc,
                                                const float* __restrict__ ewt,
                                                float* __restrict__ msg) {
  int t = blockIdx.x * 256 + threadIdx.x;
  int n = t >> 4, p = t & 15;
  if (n >= NN) return;
  int beg = row_ptr[n], end = row_ptr[n + 1];
  float ax = 0.f, ay = 0.f, az = 0.f, aw = 0.f;
  for (int i = beg; i < end; ++i) {
    int s = esrc[i];
    float we = ewt[i];
    float4 v = ((const float4*)(h + (size_t)s * D))[p];
    ax = fmaf(v.x, we, ax);
    ay = fmaf(v.y, we, ay);
    az = fmaf(v.z, we, az);
    aw = fmaf(v.w, we, aw);
  }
  float4 o = {ax, ay, az, aw};
  ((float4*)(msg + (size_t)n * D))[p] = o;
}

// ---------------- h_next = relu(relu((h+msg)@W1+b1)@W2+b2), in-place over msg
__global__ __launch_bounds__(256) void k_gin(const float* __restrict__ h,
                                             float* mh,  // msg in, h_next out
                                             const float* __restrict__ W1,
                                             const float* __restrict__ b1,
                                             const float* __restrict__ W2,
                                             const float* __restrict__ b2) {
  __shared__ float sW1[D * D];
  __shared__ float sW2[D * D];
  __shared__ float sb1[D], sb2[D];
  for (int i = threadIdx.x; i < D * D; i += 256) { sW1[i] = W1[i]; sW2[i] = W2[i]; }
  if (threadIdx.x < D) { sb1[threadIdx.x] = b1[threadIdx.x]; sb2[threadIdx.x] = b2[threadIdx.x]; }
  __syncthreads();
  int node = blockIdx.x * 256 + threadIdx.x;
  if (node >= NN) return;
  const float4* hp = (const float4*)(h + (size_t)node * D);
  const float4* mp = (const float4*)(mh + (size_t)node * D);
  float v[D];
#pragma unroll
  for (int i = 0; i < D / 4; ++i) {
    float4 a = hp[i];
    float4 b = mp[i];
    v[4 * i + 0] = a.x + b.x;
    v[4 * i + 1] = a.y + b.y;
    v[4 * i + 2] = a.z + b.z;
    v[4 * i + 3] = a.w + b.w;
  }
  float tt[D];
#pragma unroll
  for (int j = 0; j < D; j += 4) {
    float a0 = sb1[j + 0], a1 = sb1[j + 1], a2 = sb1[j + 2], a3 = sb1[j + 3];
#pragma unroll
    for (int k = 0; k < D; ++k) {
      float vk = v[k];
      a0 = fmaf(vk, sW1[k * D + j + 0], a0);
      a1 = fmaf(vk, sW1[k * D + j + 1], a1);
      a2 = fmaf(vk, sW1[k * D + j + 2], a2);
      a3 = fmaf(vk, sW1[k * D + j + 3], a3);
    }
    tt[j + 0] = fmaxf(a0, 0.f);
    tt[j + 1] = fmaxf(a1, 0.f);
    tt[j + 2] = fmaxf(a2, 0.f);
    tt[j + 3] = fmaxf(a3, 0.f);
  }
  float4* op = (float4*)(mh + (size_t)node * D);
#pragma unroll
  for (int j = 0; j < D; j += 4) {
    float a0 = sb2[j + 0], a1 = sb2[j + 1], a2 = sb2[j + 2], a3 = sb2[j + 3];
#pragma unroll
    for (int k = 0; k < D; ++k) {
      float tk = tt[k];
      a0 = fmaf(tk, sW2[k * D + j + 0], a0);
      a1 = fmaf(tk, sW2[k * D + j + 1], a1);
      a2 = fmaf(tk, sW2[k * D + j + 2], a2);
      a3 = fmaf(tk, sW2[k * D + j + 3], a3);
    }
    float4 o;
    o.x = fmaxf(a0, 0.f);
    o.y = fmaxf(a1, 0.f);
    o.z = fmaxf(a2, 0.f);
    o.w = fmaxf(a3, 0.f);
    op[j >> 2] = o;
  }
}

// ---------------- per-feature sum / sumsq over nodes ----------------
__global__ __launch_bounds__(256) void k_bnstats(const float* __restrict__ h,
                                                 float* __restrict__ stats) {
  __shared__ float ss[256];
  __shared__ float sq[256];
  int f = threadIdx.x & (D - 1);
  int sub = threadIdx.x >> 6;  // 0..3
  float s = 0.f, q = 0.f;
  for (int n = blockIdx.x * 4 + sub; n < NN; n += gridDim.x * 4) {
    float x = h[(size_t)n * D + f];
    s += x;
    q += x * x;
  }
  ss[threadIdx.x] = s;
  sq[threadIdx.x] = q;
  __syncthreads();
  if (threadIdx.x < D) {
    s = ss[threadIdx.x] + ss[threadIdx.x + 64] + ss[threadIdx.x + 128] + ss[threadIdx.x + 192];
    q = sq[threadIdx.x] + sq[threadIdx.x + 64] + sq[threadIdx.x + 128] + sq[threadIdx.x + 192];
    unsafeAtomicAdd(&stats[f], s);
    unsafeAtomicAdd(&stats[D + f], q);
  }
}

// stats[128..191] = scale, stats[192..255] = shift
__global__ void k_bnfin(float* stats, const float* __restrict__ gamma,
                        const float* __restrict__ beta) {
  int f = threadIdx.x;  // 64 threads
  float mean = stats[f] * (1.0f / NN);
  float var = stats[D + f] * (1.0f / NN) - mean * mean;
  var = fmaxf(var, 0.f);
  float sc = gamma[f] * rsqrtf(var + BN_EPS);
  stats[2 * D + f] = sc;
  stats[3 * D + f] = beta[f] - mean * sc;
}

// ---------------- apply BN, write h_cur, accumulate pooled ----------------
__global__ __launch_bounds__(256) void k_bnapply(const float* __restrict__ hin,
                                                 const float* __restrict__ stats,
                                                 const int* __restrict__ batch,
                                                 float* __restrict__ hout,
                                                 float* __restrict__ pooled,
                                                 int layer) {
  int gid = blockIdx.x * 256 + threadIdx.x;
  if (gid >= NN * 16) return;
  int n = gid >> 4, p = gid & 15;
  float4 x = ((const float4*)(hin + (size_t)n * D))[p];
  float4 sc = ((const float4*)(stats + 2 * D))[p];
  float4 sh = ((const float4*)(stats + 3 * D))[p];
  float4 o;
  o.x = fmaf(x.x, sc.x, sh.x);
  o.y = fmaf(x.y, sc.y, sh.y);
  o.z = fmaf(x.z, sc.z, sh.z);
  o.w = fmaf(x.w, sc.w, sh.w);
  ((float4*)(hout + (size_t)n * D))[p] = o;
  int g = batch[n];
  float* pp = pooled + (size_t)g * EMBD + layer * D + p * 4;
  unsafeAtomicAdd(pp + 0, o.x);
  unsafeAtomicAdd(pp + 1, o.y);
  unsafeAtomicAdd(pp + 2, o.z);
  unsafeAtomicAdd(pp + 3, o.w);
}

// ---------------- projection head: one block (320 thr) per graph ----------
__global__ __launch_bounds__(EMBD) void k_proj(const float* __restrict__ pooled,
                                               const float* __restrict__ counts,
                                               const float* __restrict__ pW1,
                                               const float* __restrict__ pb1,
                                               const float* __restrict__ pW2,
                                               const float* __restrict__ pb2,
                                               float* __restrict__ out) {
  __shared__ float row[EMBD];
  __shared__ float y1[EMBD];
  int g = blockIdx.x, j = threadIdx.x;
  float cnt = fmaxf(counts[g], 1.0f);
  row[j] = pooled[(size_t)g * EMBD + j] / cnt;
  __syncthreads();
  float acc = pb1[j];
#pragma unroll 4
  for (int k = 0; k < EMBD; ++k) acc = fmaf(row[k], pW1[(size_t)k * EMBD + j], acc);
  y1[j] = fmaxf(acc, 0.f);
  __syncthreads();
  acc = pb2[j];
#pragma unroll 4
  for (int k = 0; k < EMBD; ++k) acc = fmaf(y1[k], pW2[(size_t)k * EMBD + j], acc);
  out[(size_t)g * EMBD + j] = acc;
}

extern "C" void kernel_launch(void* const* d_in, const int* in_sizes, int n_in,
                              void* d_out, int out_size, void* d_ws, size_t ws_size,
                              hipStream_t stream) {
  const float* x = (const float*)d_in[0];
  const int* ei = (const int*)d_in[1];
  const float* ew = (const float*)d_in[2];
  const int* batch = (const int*)d_in[3];
  const float* W1s = (const float*)d_in[4];
  const float* b1s = (const float*)d_in[5];
  const float* W2s = (const float*)d_in[6];
  const float* b2s = (const float*)d_in[7];
  const float* gammas = (const float*)d_in[8];
  const float* betas = (const float*)d_in[9];
  const float* pW1 = (const float*)d_in[10];
  const float* pb1 = (const float*)d_in[11];
  const float* pW2 = (const float*)d_in[12];
  const float* pb2 = (const float*)d_in[13];
  const int* srcv = ei;
  const int* dstv = ei + NE;

  char* ws = (char*)d_ws;
  float* msg = (float*)ws;                               // NN*D
  float* hcur = msg + (size_t)NN * D;                    // NN*D
  float* stats = hcur + (size_t)NN * D;                  // 256
  float* pooled = stats + 256;                           // NG*EMBD
  float* counts = pooled + (size_t)NG * EMBD;            // NG
  int* row_ptr = (int*)(counts + NG);                    // NN+1 (doubles as deg)
  int* cursor = row_ptr + NN + 1;                        // NN
  int* esrc = cursor + NN;                               // NE
  float* ewt = (float*)(esrc + NE);                      // NE

  // ---- one-time (per call) CSR build ----
  hipMemsetAsync(row_ptr, 0, (NN + 1) * sizeof(int), stream);
  k_hist<<<(NE + 255) / 256, 256, 0, stream>>>(dstv, row_ptr);
  k_scan<<<1, 1024, 0, stream>>>(row_ptr, cursor);
  k_fill<<<(NE + 255) / 256, 256, 0, stream>>>(srcv, dstv, ew, cursor, esrc, ewt);

  // zero pooled + counts (contiguous)
  hipMemsetAsync(pooled, 0, ((size_t)NG * EMBD + NG) * sizeof(float), stream);
  k_counts<<<(NN + 255) / 256, 256, 0, stream>>>(batch, counts);

  const float* hin = x;
  for (int L = 0; L < NL; ++L) {
    hipMemsetAsync(stats, 0, 256 * sizeof(float), stream);
    k_gather<<<(NN * 16 + 255) / 256, 256, 0, stream>>>(hin, row_ptr, esrc, ewt, msg);
    k_gin<<<(NN + 255) / 256, 256, 0, stream>>>(hin, msg, W1s + L * D * D, b1s + L * D,
                                                W2s + L * D * D, b2s + L * D);
    k_bnstats<<<512, 256, 0, stream>>>(msg, stats);
    k_bnfin<<<1, 64, 0, stream>>>(stats, gammas + L * D, betas + L * D);
    k_bnapply<<<(NN * 16 + 255) / 256, 256, 0, stream>>>(msg, stats, batch, hcur, pooled, L);
    hin = hcur;
  }
  k_proj<<<NG, EMBD, 0, stream>>>(pooled, counts, pW1, pb1, pW2, pb2, (float*)d_out);
}

// Round 3
// 2014.242 us; speedup vs baseline: 4.1045x; 1.1210x over previous
//
#include <hip/hip_runtime.h>

#define NN 100000
#define NE 1600000
#define D 64
#define NL 5
#define NG 1024
#define EMBD 320
#define BN_EPS 1e-5f
#define SCAN_NB ((NN + 255) / 256)  // 391

// ---------------- counts[g] = #nodes in graph g ----------------
__global__ __launch_bounds__(256) void k_counts(const int* __restrict__ batch,
                                                float* __restrict__ counts) {
  int i = blockIdx.x * 256 + threadIdx.x;
  if (i < NN) unsafeAtomicAdd(&counts[batch[i]], 1.0f);
}

// ---------------- CSR build: histogram of dst ----------------
__global__ __launch_bounds__(256) void k_hist(const int* __restrict__ dst,
                                              int* __restrict__ deg) {
  int e = blockIdx.x * 256 + threadIdx.x;
  if (e < NE) atomicAdd(&deg[dst[e]], 1);
}

// ---------------- parallel exclusive scan, 3 phases ----------------
__global__ __launch_bounds__(256) void k_scan1(const int* __restrict__ deg,
                                               int* __restrict__ bsums) {
  __shared__ int sh[256];
  int i = blockIdx.x * 256 + threadIdx.x;
  sh[threadIdx.x] = (i < NN) ? deg[i] : 0;
  __syncthreads();
  for (int off = 128; off > 0; off >>= 1) {
    if (threadIdx.x < off) sh[threadIdx.x] += sh[threadIdx.x + off];
    __syncthreads();
  }
  if (threadIdx.x == 0) bsums[blockIdx.x] = sh[0];
}

__global__ __launch_bounds__(512) void k_scan2(int* __restrict__ bsums) {
  __shared__ int sh[512];
  int t = threadIdx.x;
  int v = (t < SCAN_NB) ? bsums[t] : 0;
  sh[t] = v;
  __syncthreads();
  for (int off = 1; off < 512; off <<= 1) {
    int u = (t >= off) ? sh[t - off] : 0;
    __syncthreads();
    sh[t] += u;
    __syncthreads();
  }
  if (t < SCAN_NB) bsums[t] = sh[t] - v;  // exclusive
}

__global__ __launch_bounds__(256) void k_scan3(int* __restrict__ row_ptr,
                                               int* __restrict__ cursor,
                                               const int* __restrict__ bsums) {
  __shared__ int sh[256];
  int t = threadIdx.x;
  int i = blockIdx.x * 256 + t;
  int v = (i < NN) ? row_ptr[i] : 0;
  sh[t] = v;
  __syncthreads();
  for (int off = 1; off < 256; off <<= 1) {
    int u = (t >= off) ? sh[t - off] : 0;
    __syncthreads();
    sh[t] += u;
    __syncthreads();
  }
  int excl = sh[t] - v + bsums[blockIdx.x];
  if (i < NN) {
    row_ptr[i] = excl;
    cursor[i] = excl;
    if (i == NN - 1) row_ptr[NN] = excl + v;
  }
}

// ---------------- fill CSR (src, weight) ----------------
__global__ __launch_bounds__(256) void k_fill(const int* __restrict__ src,
                                              const int* __restrict__ dst,
                                              const float* __restrict__ w,
                                              int* __restrict__ cursor,
                                              int* __restrict__ esrc,
                                              float* __restrict__ ewt) {
  int e = blockIdx.x * 256 + threadIdx.x;
  if (e >= NE) return;
  int slot = atomicAdd(&cursor[dst[e]], 1);
  esrc[slot] = src[e];
  ewt[slot] = w[e];
}

// ---------------- msg[n] = sum_{e in row n} w_e * h[src_e]  (16 thr/node) --
__global__ __launch_bounds__(256) void k_gather(const float* __restrict__ h,
                                                const int* __restrict__ row_ptr,
                                                const int* __restrict__ esrc,
                                                const float* __restrict__ ewt,
                                                float* __restrict__ msg) {
  int t = blockIdx.x * 256 + threadIdx.x;
  int n = t >> 4, p = t & 15;
  if (n >= NN) return;
  int beg = row_ptr[n], end = row_ptr[n + 1];
  float ax = 0.f, ay = 0.f, az = 0.f, aw = 0.f;
  for (int i = beg; i < end; ++i) {
    int s = esrc[i];
    float we = ewt[i];
    float4 v = ((const float4*)(h + (size_t)s * D))[p];
    ax = fmaf(v.x, we, ax);
    ay = fmaf(v.y, we, ay);
    az = fmaf(v.z, we, az);
    aw = fmaf(v.w, we, aw);
  }
  float4 o = {ax, ay, az, aw};
  ((float4*)(msg + (size_t)n * D))[p] = o;
}

// ---------------- h_next = relu(relu((h+msg)@W1+b1)@W2+b2), in-place over msg
__global__ __launch_bounds__(256) void k_gin(const float* __restrict__ h,
                                             float* mh,  // msg in, h_next out
                                             const float* __restrict__ W1,
                                             const float* __restrict__ b1,
                                             const float* __restrict__ W2,
                                             const float* __restrict__ b2) {
  __shared__ float sW1[D * D];
  __shared__ float sW2[D * D];
  __shared__ float sb1[D], sb2[D];
  for (int i = threadIdx.x; i < D * D; i += 256) { sW1[i] = W1[i]; sW2[i] = W2[i]; }
  if (threadIdx.x < D) { sb1[threadIdx.x] = b1[threadIdx.x]; sb2[threadIdx.x] = b2[threadIdx.x]; }
  __syncthreads();
  int node = blockIdx.x * 256 + threadIdx.x;
  if (node >= NN) return;
  const float4* hp = (const float4*)(h + (size_t)node * D);
  const float4* mp = (const float4*)(mh + (size_t)node * D);
  float v[D];
#pragma unroll
  for (int i = 0; i < D / 4; ++i) {
    float4 a = hp[i];
    float4 b = mp[i];
    v[4 * i + 0] = a.x + b.x;
    v[4 * i + 1] = a.y + b.y;
    v[4 * i + 2] = a.z + b.z;
    v[4 * i + 3] = a.w + b.w;
  }
  float tt[D];
#pragma unroll
  for (int j = 0; j < D; j += 4) {
    float a0 = sb1[j + 0], a1 = sb1[j + 1], a2 = sb1[j + 2], a3 = sb1[j + 3];
#pragma unroll
    for (int k = 0; k < D; ++k) {
      float vk = v[k];
      a0 = fmaf(vk, sW1[k * D + j + 0], a0);
      a1 = fmaf(vk, sW1[k * D + j + 1], a1);
      a2 = fmaf(vk, sW1[k * D + j + 2], a2);
      a3 = fmaf(vk, sW1[k * D + j + 3], a3);
    }
    tt[j + 0] = fmaxf(a0, 0.f);
    tt[j + 1] = fmaxf(a1, 0.f);
    tt[j + 2] = fmaxf(a2, 0.f);
    tt[j + 3] = fmaxf(a3, 0.f);
  }
  float4* op = (float4*)(mh + (size_t)node * D);
#pragma unroll
  for (int j = 0; j < D; j += 4) {
    float a0 = sb2[j + 0], a1 = sb2[j + 1], a2 = sb2[j + 2], a3 = sb2[j + 3];
#pragma unroll
    for (int k = 0; k < D; ++k) {
      float tk = tt[k];
      a0 = fmaf(tk, sW2[k * D + j + 0], a0);
      a1 = fmaf(tk, sW2[k * D + j + 1], a1);
      a2 = fmaf(tk, sW2[k * D + j + 2], a2);
      a3 = fmaf(tk, sW2[k * D + j + 3], a3);
    }
    float4 o;
    o.x = fmaxf(a0, 0.f);
    o.y = fmaxf(a1, 0.f);
    o.z = fmaxf(a2, 0.f);
    o.w = fmaxf(a3, 0.f);
    op[j >> 2] = o;
  }
}

// ---------------- per-feature sum / sumsq over nodes ----------------
__global__ __launch_bounds__(256) void k_bnstats(const float* __restrict__ h,
                                                 float* __restrict__ stats) {
  __shared__ float ss[256];
  __shared__ float sq[256];
  int f = threadIdx.x & (D - 1);
  int sub = threadIdx.x >> 6;  // 0..3
  float s = 0.f, q = 0.f;
  for (int n = blockIdx.x * 4 + sub; n < NN; n += gridDim.x * 4) {
    float x = h[(size_t)n * D + f];
    s += x;
    q += x * x;
  }
  ss[threadIdx.x] = s;
  sq[threadIdx.x] = q;
  __syncthreads();
  if (threadIdx.x < D) {
    s = ss[threadIdx.x] + ss[threadIdx.x + 64] + ss[threadIdx.x + 128] + ss[threadIdx.x + 192];
    q = sq[threadIdx.x] + sq[threadIdx.x + 64] + sq[threadIdx.x + 128] + sq[threadIdx.x + 192];
    unsafeAtomicAdd(&stats[f], s);
    unsafeAtomicAdd(&stats[D + f], q);
  }
}

// stats[128..191] = scale, stats[192..255] = shift
__global__ void k_bnfin(float* stats, const float* __restrict__ gamma,
                        const float* __restrict__ beta) {
  int f = threadIdx.x;  // 64 threads
  float mean = stats[f] * (1.0f / NN);
  float var = stats[D + f] * (1.0f / NN) - mean * mean;
  var = fmaxf(var, 0.f);
  float sc = gamma[f] * rsqrtf(var + BN_EPS);
  stats[2 * D + f] = sc;
  stats[3 * D + f] = beta[f] - mean * sc;
}

// ---------------- apply BN, write h_cur, accumulate pooled ----------------
__global__ __launch_bounds__(256) void k_bnapply(const float* __restrict__ hin,
                                                 const float* __restrict__ stats,
                                                 const int* __restrict__ batch,
                                                 float* __restrict__ hout,
                                                 float* __restrict__ pooled,
                                                 int layer) {
  int gid = blockIdx.x * 256 + threadIdx.x;
  if (gid >= NN * 16) return;
  int n = gid >> 4, p = gid & 15;
  float4 x = ((const float4*)(hin + (size_t)n * D))[p];
  float4 sc = ((const float4*)(stats + 2 * D))[p];
  float4 sh = ((const float4*)(stats + 3 * D))[p];
  float4 o;
  o.x = fmaf(x.x, sc.x, sh.x);
  o.y = fmaf(x.y, sc.y, sh.y);
  o.z = fmaf(x.z, sc.z, sh.z);
  o.w = fmaf(x.w, sc.w, sh.w);
  ((float4*)(hout + (size_t)n * D))[p] = o;
  int g = batch[n];
  float* pp = pooled + (size_t)g * EMBD + layer * D + p * 4;
  unsafeAtomicAdd(pp + 0, o.x);
  unsafeAtomicAdd(pp + 1, o.y);
  unsafeAtomicAdd(pp + 2, o.z);
  unsafeAtomicAdd(pp + 3, o.w);
}

// ---------------- projection head: one block (320 thr) per graph ----------
__global__ __launch_bounds__(EMBD) void k_proj(const float* __restrict__ pooled,
                                               const float* __restrict__ counts,
                                               const float* __restrict__ pW1,
                                               const float* __restrict__ pb1,
                                               const float* __restrict__ pW2,
                                               const float* __restrict__ pb2,
                                               float* __restrict__ out) {
  __shared__ float row[EMBD];
  __shared__ float y1[EMBD];
  int g = blockIdx.x, j = threadIdx.x;
  float cnt = fmaxf(counts[g], 1.0f);
  row[j] = pooled[(size_t)g * EMBD + j] / cnt;
  __syncthreads();
  float acc = pb1[j];
#pragma unroll 4
  for (int k = 0; k < EMBD; ++k) acc = fmaf(row[k], pW1[(size_t)k * EMBD + j], acc);
  y1[j] = fmaxf(acc, 0.f);
  __syncthreads();
  acc = pb2[j];
#pragma unroll 4
  for (int k = 0; k < EMBD; ++k) acc = fmaf(y1[k], pW2[(size_t)k * EMBD + j], acc);
  out[(size_t)g * EMBD + j] = acc;
}

extern "C" void kernel_launch(void* const* d_in, const int* in_sizes, int n_in,
                              void* d_out, int out_size, void* d_ws, size_t ws_size,
                              hipStream_t stream) {
  const float* x = (const float*)d_in[0];
  const int* ei = (const int*)d_in[1];
  const float* ew = (const float*)d_in[2];
  const int* batch = (const int*)d_in[3];
  const float* W1s = (const float*)d_in[4];
  const float* b1s = (const float*)d_in[5];
  const float* W2s = (const float*)d_in[6];
  const float* b2s = (const float*)d_in[7];
  const float* gammas = (const float*)d_in[8];
  const float* betas = (const float*)d_in[9];
  const float* pW1 = (const float*)d_in[10];
  const float* pb1 = (const float*)d_in[11];
  const float* pW2 = (const float*)d_in[12];
  const float* pb2 = (const float*)d_in[13];
  const int* srcv = ei;
  const int* dstv = ei + NE;

  char* ws = (char*)d_ws;
  float* msg = (float*)ws;                               // NN*D
  float* hcur = msg + (size_t)NN * D;                    // NN*D
  float* stats = hcur + (size_t)NN * D;                  // 256
  float* pooled = stats + 256;                           // NG*EMBD
  float* counts = pooled + (size_t)NG * EMBD;            // NG
  int* row_ptr = (int*)(counts + NG);                    // NN+1 (doubles as deg)
  int* cursor = row_ptr + NN + 1;                        // NN
  int* esrc = cursor + NN;                               // NE
  float* ewt = (float*)(esrc + NE);                      // NE
  int* bsums = (int*)(ewt + NE);                         // SCAN_NB

  // ---- CSR build (per call; input edge_index is constant so result is too) --
  hipMemsetAsync(row_ptr, 0, (NN + 1) * sizeof(int), stream);
  k_hist<<<(NE + 255) / 256, 256, 0, stream>>>(dstv, row_ptr);
  k_scan1<<<SCAN_NB, 256, 0, stream>>>(row_ptr, bsums);
  k_scan2<<<1, 512, 0, stream>>>(bsums);
  k_scan3<<<SCAN_NB, 256, 0, stream>>>(row_ptr, cursor, bsums);
  k_fill<<<(NE + 255) / 256, 256, 0, stream>>>(srcv, dstv, ew, cursor, esrc, ewt);

  // zero pooled + counts (contiguous)
  hipMemsetAsync(pooled, 0, ((size_t)NG * EMBD + NG) * sizeof(float), stream);
  k_counts<<<(NN + 255) / 256, 256, 0, stream>>>(batch, counts);

  const float* hin = x;
  for (int L = 0; L < NL; ++L) {
    hipMemsetAsync(stats, 0, 256 * sizeof(float), stream);
    k_gather<<<(NN * 16 + 255) / 256, 256, 0, stream>>>(hin, row_ptr, esrc, ewt, msg);
    k_gin<<<(NN + 255) / 256, 256, 0, stream>>>(hin, msg, W1s + L * D * D, b1s + L * D,
                                                W2s + L * D * D, b2s + L * D);
    k_bnstats<<<512, 256, 0, stream>>>(msg, stats);
    k_bnfin<<<1, 64, 0, stream>>>(stats, gammas + L * D, betas + L * D);
    k_bnapply<<<(NN * 16 + 255) / 256, 256, 0, stream>>>(msg, stats, batch, hcur, pooled, L);
    hin = hcur;
  }
  k_proj<<<NG, EMBD, 0, stream>>>(pooled, counts, pW1, pb1, pW2, pb2, (float*)d_out);
}

// Round 4
// 1258.044 us; speedup vs baseline: 6.5717x; 1.6011x over previous
//
#include <hip/hip_runtime.h>

#define NN 100000
#define NE 1600000
#define D 64
#define NL 5
#define NG 1024
#define EMBD 320
#define BN_EPS 1e-5f
#define SCAN_NB ((NN + 255) / 256)  // 391

// ---------------- graph boundaries from sorted batch ----------------
// gstart[g] = first node index of graph g; gstart[NG] = NN.
__global__ __launch_bounds__(256) void k_gbound(const int* __restrict__ batch,
                                                int* __restrict__ gstart) {
  int i = blockIdx.x * 256 + threadIdx.x;
  if (i >= NN) return;
  int b = batch[i];
  int bp = (i == 0) ? -1 : batch[i - 1];
  for (int g = bp + 1; g <= b; ++g) gstart[g] = i;
  if (i == NN - 1) {
    for (int g = b + 1; g <= NG; ++g) gstart[g] = NN;
  }
}

// ---------------- CSR build: histogram of dst ----------------
__global__ __launch_bounds__(256) void k_hist(const int* __restrict__ dst,
                                              int* __restrict__ deg) {
  int e = blockIdx.x * 256 + threadIdx.x;
  if (e < NE) atomicAdd(&deg[dst[e]], 1);
}

// ---------------- parallel exclusive scan, 3 phases ----------------
__global__ __launch_bounds__(256) void k_scan1(const int* __restrict__ deg,
                                               int* __restrict__ bsums) {
  __shared__ int sh[256];
  int i = blockIdx.x * 256 + threadIdx.x;
  sh[threadIdx.x] = (i < NN) ? deg[i] : 0;
  __syncthreads();
  for (int off = 128; off > 0; off >>= 1) {
    if (threadIdx.x < off) sh[threadIdx.x] += sh[threadIdx.x + off];
    __syncthreads();
  }
  if (threadIdx.x == 0) bsums[blockIdx.x] = sh[0];
}

__global__ __launch_bounds__(512) void k_scan2(int* __restrict__ bsums) {
  __shared__ int sh[512];
  int t = threadIdx.x;
  int v = (t < SCAN_NB) ? bsums[t] : 0;
  sh[t] = v;
  __syncthreads();
  for (int off = 1; off < 512; off <<= 1) {
    int u = (t >= off) ? sh[t - off] : 0;
    __syncthreads();
    sh[t] += u;
    __syncthreads();
  }
  if (t < SCAN_NB) bsums[t] = sh[t] - v;  // exclusive
}

__global__ __launch_bounds__(256) void k_scan3(int* __restrict__ row_ptr,
                                               int* __restrict__ cursor,
                                               const int* __restrict__ bsums) {
  __shared__ int sh[256];
  int t = threadIdx.x;
  int i = blockIdx.x * 256 + t;
  int v = (i < NN) ? row_ptr[i] : 0;
  sh[t] = v;
  __syncthreads();
  for (int off = 1; off < 256; off <<= 1) {
    int u = (t >= off) ? sh[t - off] : 0;
    __syncthreads();
    sh[t] += u;
    __syncthreads();
  }
  int excl = sh[t] - v + bsums[blockIdx.x];
  if (i < NN) {
    row_ptr[i] = excl;
    cursor[i] = excl;
    if (i == NN - 1) row_ptr[NN] = excl + v;
  }
}

// ---------------- fill CSR (src, weight) ----------------
__global__ __launch_bounds__(256) void k_fill(const int* __restrict__ src,
                                              const int* __restrict__ dst,
                                              const float* __restrict__ w,
                                              int* __restrict__ cursor,
                                              int* __restrict__ esrc,
                                              float* __restrict__ ewt) {
  int e = blockIdx.x * 256 + threadIdx.x;
  if (e >= NE) return;
  int slot = atomicAdd(&cursor[dst[e]], 1);
  esrc[slot] = src[e];
  ewt[slot] = w[e];
}

// ---------------- msg[n] = sum_{e in row n} w_e * h[src_e]  (16 thr/node) --
__global__ __launch_bounds__(256) void k_gather(const float* __restrict__ h,
                                                const int* __restrict__ row_ptr,
                                                const int* __restrict__ esrc,
                                                const float* __restrict__ ewt,
                                                float* __restrict__ msg) {
  int t = blockIdx.x * 256 + threadIdx.x;
  int n = t >> 4, p = t & 15;
  if (n >= NN) return;
  int beg = row_ptr[n], end = row_ptr[n + 1];
  float ax = 0.f, ay = 0.f, az = 0.f, aw = 0.f;
  for (int i = beg; i < end; ++i) {
    int s = esrc[i];
    float we = ewt[i];
    float4 v = ((const float4*)(h + (size_t)s * D))[p];
    ax = fmaf(v.x, we, ax);
    ay = fmaf(v.y, we, ay);
    az = fmaf(v.z, we, az);
    aw = fmaf(v.w, we, aw);
  }
  float4 o = {ax, ay, az, aw};
  ((float4*)(msg + (size_t)n * D))[p] = o;
}

// ---------------- h_next = relu(relu((h+msg)@W1+b1)@W2+b2), in-place over msg
__global__ __launch_bounds__(256) void k_gin(const float* __restrict__ h,
                                             float* mh,  // msg in, h_next out
                                             const float* __restrict__ W1,
                                             const float* __restrict__ b1,
                                             const float* __restrict__ W2,
                                             const float* __restrict__ b2) {
  __shared__ float sW1[D * D];
  __shared__ float sW2[D * D];
  __shared__ float sb1[D], sb2[D];
  for (int i = threadIdx.x; i < D * D; i += 256) { sW1[i] = W1[i]; sW2[i] = W2[i]; }
  if (threadIdx.x < D) { sb1[threadIdx.x] = b1[threadIdx.x]; sb2[threadIdx.x] = b2[threadIdx.x]; }
  __syncthreads();
  int node = blockIdx.x * 256 + threadIdx.x;
  if (node >= NN) return;
  const float4* hp = (const float4*)(h + (size_t)node * D);
  const float4* mp = (const float4*)(mh + (size_t)node * D);
  float v[D];
#pragma unroll
  for (int i = 0; i < D / 4; ++i) {
    float4 a = hp[i];
    float4 b = mp[i];
    v[4 * i + 0] = a.x + b.x;
    v[4 * i + 1] = a.y + b.y;
    v[4 * i + 2] = a.z + b.z;
    v[4 * i + 3] = a.w + b.w;
  }
  float tt[D];
#pragma unroll
  for (int j = 0; j < D; j += 4) {
    float a0 = sb1[j + 0], a1 = sb1[j + 1], a2 = sb1[j + 2], a3 = sb1[j + 3];
#pragma unroll
    for (int k = 0; k < D; ++k) {
      float vk = v[k];
      a0 = fmaf(vk, sW1[k * D + j + 0], a0);
      a1 = fmaf(vk, sW1[k * D + j + 1], a1);
      a2 = fmaf(vk, sW1[k * D + j + 2], a2);
      a3 = fmaf(vk, sW1[k * D + j + 3], a3);
    }
    tt[j + 0] = fmaxf(a0, 0.f);
    tt[j + 1] = fmaxf(a1, 0.f);
    tt[j + 2] = fmaxf(a2, 0.f);
    tt[j + 3] = fmaxf(a3, 0.f);
  }
  float4* op = (float4*)(mh + (size_t)node * D);
#pragma unroll
  for (int j = 0; j < D; j += 4) {
    float a0 = sb2[j + 0], a1 = sb2[j + 1], a2 = sb2[j + 2], a3 = sb2[j + 3];
#pragma unroll
    for (int k = 0; k < D; ++k) {
      float tk = tt[k];
      a0 = fmaf(tk, sW2[k * D + j + 0], a0);
      a1 = fmaf(tk, sW2[k * D + j + 1], a1);
      a2 = fmaf(tk, sW2[k * D + j + 2], a2);
      a3 = fmaf(tk, sW2[k * D + j + 3], a3);
    }
    float4 o;
    o.x = fmaxf(a0, 0.f);
    o.y = fmaxf(a1, 0.f);
    o.z = fmaxf(a2, 0.f);
    o.w = fmaxf(a3, 0.f);
    op[j >> 2] = o;
  }
}

// ---------------- per-feature sum / sumsq over nodes ----------------
__global__ __launch_bounds__(256) void k_bnstats(const float* __restrict__ h,
                                                 float* __restrict__ stats) {
  __shared__ float ss[256];
  __shared__ float sq[256];
  int f = threadIdx.x & (D - 1);
  int sub = threadIdx.x >> 6;  // 0..3
  float s = 0.f, q = 0.f;
  for (int n = blockIdx.x * 4 + sub; n < NN; n += gridDim.x * 4) {
    float x = h[(size_t)n * D + f];
    s += x;
    q += x * x;
  }
  ss[threadIdx.x] = s;
  sq[threadIdx.x] = q;
  __syncthreads();
  if (threadIdx.x < D) {
    s = ss[threadIdx.x] + ss[threadIdx.x + 64] + ss[threadIdx.x + 128] + ss[threadIdx.x + 192];
    q = sq[threadIdx.x] + sq[threadIdx.x + 64] + sq[threadIdx.x + 128] + sq[threadIdx.x + 192];
    unsafeAtomicAdd(&stats[f], s);
    unsafeAtomicAdd(&stats[D + f], q);
  }
}

// stats[128..191] = scale, stats[192..255] = shift
__global__ void k_bnfin(float* stats, const float* __restrict__ gamma,
                        const float* __restrict__ beta) {
  int f = threadIdx.x;  // 64 threads
  float mean = stats[f] * (1.0f / NN);
  float var = stats[D + f] * (1.0f / NN) - mean * mean;
  var = fmaxf(var, 0.f);
  float sc = gamma[f] * rsqrtf(var + BN_EPS);
  stats[2 * D + f] = sc;
  stats[3 * D + f] = beta[f] - mean * sc;
}

// ---------------- apply BN, write h_cur (no atomics) ----------------
__global__ __launch_bounds__(256) void k_bnapply(const float* __restrict__ hin,
                                                 const float* __restrict__ stats,
                                                 float* __restrict__ hout) {
  int gid = blockIdx.x * 256 + threadIdx.x;
  if (gid >= NN * 16) return;
  int n = gid >> 4, p = gid & 15;
  float4 x = ((const float4*)(hin + (size_t)n * D))[p];
  float4 sc = ((const float4*)(stats + 2 * D))[p];
  float4 sh = ((const float4*)(stats + 3 * D))[p];
  float4 o;
  o.x = fmaf(x.x, sc.x, sh.x);
  o.y = fmaf(x.y, sc.y, sh.y);
  o.z = fmaf(x.z, sc.z, sh.z);
  o.w = fmaf(x.w, sc.w, sh.w);
  ((float4*)(hout + (size_t)n * D))[p] = o;
}

// ---------------- per-graph mean pool (sorted batch, no atomics) ----------
__global__ __launch_bounds__(256) void k_pool(const float* __restrict__ h,
                                              const int* __restrict__ gstart,
                                              float* __restrict__ pooled,
                                              int layer) {
  __shared__ float sh[256];
  int g = blockIdx.x;
  int beg = gstart[g], end = gstart[g + 1];
  int f = threadIdx.x & 63, r = threadIdx.x >> 6;
  float s = 0.f;
  for (int n = beg + r; n < end; n += 4) s += h[(size_t)n * D + f];
  sh[threadIdx.x] = s;
  __syncthreads();
  if (threadIdx.x < 64) {
    float tot = sh[f] + sh[f + 64] + sh[f + 128] + sh[f + 192];
    int cnt = end - beg;
    float inv = 1.0f / (float)max(cnt, 1);
    pooled[(size_t)g * EMBD + layer * D + f] = tot * inv;
  }
}

// ---------------- projection head: one block (320 thr) per graph ----------
__global__ __launch_bounds__(EMBD) void k_proj(const float* __restrict__ pooled,
                                               const float* __restrict__ pW1,
                                               const float* __restrict__ pb1,
                                               const float* __restrict__ pW2,
                                               const float* __restrict__ pb2,
                                               float* __restrict__ out) {
  __shared__ float row[EMBD];
  __shared__ float y1[EMBD];
  int g = blockIdx.x, j = threadIdx.x;
  row[j] = pooled[(size_t)g * EMBD + j];
  __syncthreads();
  float acc = pb1[j];
#pragma unroll 4
  for (int k = 0; k < EMBD; ++k) acc = fmaf(row[k], pW1[(size_t)k * EMBD + j], acc);
  y1[j] = fmaxf(acc, 0.f);
  __syncthreads();
  acc = pb2[j];
#pragma unroll 4
  for (int k = 0; k < EMBD; ++k) acc = fmaf(y1[k], pW2[(size_t)k * EMBD + j], acc);
  out[(size_t)g * EMBD + j] = acc;
}

extern "C" void kernel_launch(void* const* d_in, const int* in_sizes, int n_in,
                              void* d_out, int out_size, void* d_ws, size_t ws_size,
                              hipStream_t stream) {
  const float* x = (const float*)d_in[0];
  const int* ei = (const int*)d_in[1];
  const float* ew = (const float*)d_in[2];
  const int* batch = (const int*)d_in[3];
  const float* W1s = (const float*)d_in[4];
  const float* b1s = (const float*)d_in[5];
  const float* W2s = (const float*)d_in[6];
  const float* b2s = (const float*)d_in[7];
  const float* gammas = (const float*)d_in[8];
  const float* betas = (const float*)d_in[9];
  const float* pW1 = (const float*)d_in[10];
  const float* pb1 = (const float*)d_in[11];
  const float* pW2 = (const float*)d_in[12];
  const float* pb2 = (const float*)d_in[13];
  const int* srcv = ei;
  const int* dstv = ei + NE;

  char* ws = (char*)d_ws;
  float* msg = (float*)ws;                               // NN*D
  float* hcur = msg + (size_t)NN * D;                    // NN*D
  float* stats = hcur + (size_t)NN * D;                  // 256
  float* pooled = stats + 256;                           // NG*EMBD
  int* gstart = (int*)(pooled + (size_t)NG * EMBD);      // NG+1
  int* row_ptr = gstart + NG + 1;                        // NN+1 (doubles as deg)
  int* cursor = row_ptr + NN + 1;                        // NN
  int* esrc = cursor + NN;                               // NE
  float* ewt = (float*)(esrc + NE);                      // NE
  int* bsums = (int*)(ewt + NE);                         // SCAN_NB

  // ---- CSR build + graph boundaries (per call; inputs constant) ----
  hipMemsetAsync(row_ptr, 0, (NN + 1) * sizeof(int), stream);
  k_hist<<<(NE + 255) / 256, 256, 0, stream>>>(dstv, row_ptr);
  k_scan1<<<SCAN_NB, 256, 0, stream>>>(row_ptr, bsums);
  k_scan2<<<1, 512, 0, stream>>>(bsums);
  k_scan3<<<SCAN_NB, 256, 0, stream>>>(row_ptr, cursor, bsums);
  k_fill<<<(NE + 255) / 256, 256, 0, stream>>>(srcv, dstv, ew, cursor, esrc, ewt);
  k_gbound<<<SCAN_NB, 256, 0, stream>>>(batch, gstart);

  const float* hin = x;
  for (int L = 0; L < NL; ++L) {
    hipMemsetAsync(stats, 0, 256 * sizeof(float), stream);
    k_gather<<<(NN * 16 + 255) / 256, 256, 0, stream>>>(hin, row_ptr, esrc, ewt, msg);
    k_gin<<<(NN + 255) / 256, 256, 0, stream>>>(hin, msg, W1s + L * D * D, b1s + L * D,
                                                W2s + L * D * D, b2s + L * D);
    k_bnstats<<<512, 256, 0, stream>>>(msg, stats);
    k_bnfin<<<1, 64, 0, stream>>>(stats, gammas + L * D, betas + L * D);
    k_bnapply<<<(NN * 16 + 255) / 256, 256, 0, stream>>>(msg, stats, hcur);
    k_pool<<<NG, 256, 0, stream>>>(hcur, gstart, pooled, L);
    hin = hcur;
  }
  k_proj<<<NG, EMBD, 0, stream>>>(pooled, pW1, pb1, pW2, pb2, (float*)d_out);
}

// Round 5
// 1152.756 us; speedup vs baseline: 7.1719x; 1.0913x over previous
//
#include <hip/hip_runtime.h>

#define NN 100000
#define NE 1600000
#define D 64
#define NL 5
#define NG 1024
#define EMBD 320
#define BN_EPS 1e-5f
#define SCAN_NB ((NN + 255) / 256)  // 391

// ---------------- graph boundaries from sorted batch ----------------
__global__ __launch_bounds__(256) void k_gbound(const int* __restrict__ batch,
                                                int* __restrict__ gstart) {
  int i = blockIdx.x * 256 + threadIdx.x;
  if (i >= NN) return;
  int b = batch[i];
  int bp = (i == 0) ? -1 : batch[i - 1];
  for (int g = bp + 1; g <= b; ++g) gstart[g] = i;
  if (i == NN - 1) {
    for (int g = b + 1; g <= NG; ++g) gstart[g] = NN;
  }
}

// ---------------- CSR build: histogram of dst ----------------
__global__ __launch_bounds__(256) void k_hist(const int* __restrict__ dst,
                                              int* __restrict__ deg) {
  int e = blockIdx.x * 256 + threadIdx.x;
  if (e < NE) atomicAdd(&deg[dst[e]], 1);
}

// ---------------- parallel exclusive scan, 3 phases ----------------
__global__ __launch_bounds__(256) void k_scan1(const int* __restrict__ deg,
                                               int* __restrict__ bsums) {
  __shared__ int sh[256];
  int i = blockIdx.x * 256 + threadIdx.x;
  sh[threadIdx.x] = (i < NN) ? deg[i] : 0;
  __syncthreads();
  for (int off = 128; off > 0; off >>= 1) {
    if (threadIdx.x < off) sh[threadIdx.x] += sh[threadIdx.x + off];
    __syncthreads();
  }
  if (threadIdx.x == 0) bsums[blockIdx.x] = sh[0];
}

__global__ __launch_bounds__(512) void k_scan2(int* __restrict__ bsums) {
  __shared__ int sh[512];
  int t = threadIdx.x;
  int v = (t < SCAN_NB) ? bsums[t] : 0;
  sh[t] = v;
  __syncthreads();
  for (int off = 1; off < 512; off <<= 1) {
    int u = (t >= off) ? sh[t - off] : 0;
    __syncthreads();
    sh[t] += u;
    __syncthreads();
  }
  if (t < SCAN_NB) bsums[t] = sh[t] - v;  // exclusive
}

__global__ __launch_bounds__(256) void k_scan3(int* __restrict__ row_ptr,
                                               int* __restrict__ cursor,
                                               const int* __restrict__ bsums) {
  __shared__ int sh[256];
  int t = threadIdx.x;
  int i = blockIdx.x * 256 + t;
  int v = (i < NN) ? row_ptr[i] : 0;
  sh[t] = v;
  __syncthreads();
  for (int off = 1; off < 256; off <<= 1) {
    int u = (t >= off) ? sh[t - off] : 0;
    __syncthreads();
    sh[t] += u;
    __syncthreads();
  }
  int excl = sh[t] - v + bsums[blockIdx.x];
  if (i < NN) {
    row_ptr[i] = excl;
    cursor[i] = excl;
    if (i == NN - 1) row_ptr[NN] = excl + v;
  }
}

// ---------------- fill CSR: one 8B (src, w_bits) pair per edge ----------
__global__ __launch_bounds__(256) void k_fill(const int* __restrict__ src,
                                              const int* __restrict__ dst,
                                              const float* __restrict__ w,
                                              int* __restrict__ cursor,
                                              int2* __restrict__ epair) {
  int e = blockIdx.x * 256 + threadIdx.x;
  if (e >= NE) return;
  int slot = atomicAdd(&cursor[dst[e]], 1);
  int2 p;
  p.x = src[e];
  p.y = __float_as_int(w[e]);
  epair[slot] = p;
}

// ---------------- msg[n] = sum_{e in row n} w_e * h[src_e]  (16 thr/node) --
__global__ __launch_bounds__(256) void k_gather(const float* __restrict__ h,
                                                const int* __restrict__ row_ptr,
                                                const int2* __restrict__ epair,
                                                float* __restrict__ msg) {
  int t = blockIdx.x * 256 + threadIdx.x;
  int n = t >> 4, p = t & 15;
  if (n >= NN) return;
  int beg = row_ptr[n], end = row_ptr[n + 1];
  float ax = 0.f, ay = 0.f, az = 0.f, aw = 0.f;
  for (int i = beg; i < end; ++i) {
    int2 pr = epair[i];
    int s = pr.x;
    float we = __int_as_float(pr.y);
    float4 v = ((const float4*)(h + (size_t)s * D))[p];
    ax = fmaf(v.x, we, ax);
    ay = fmaf(v.y, we, ay);
    az = fmaf(v.z, we, az);
    aw = fmaf(v.w, we, aw);
  }
  float4 o = {ax, ay, az, aw};
  ((float4*)(msg + (size_t)n * D))[p] = o;
}

// 6-step butterfly over (v, tt): half-exchange; lane ends with feature
// f = bitrev6(lane) fully reduced across the wave in v[0] / tt[0].
#define RSTEP(M, HC)                                                       \
  {                                                                        \
    const bool hi = (lane & (M)) != 0;                                     \
    _Pragma("unroll") for (int i = 0; i < (HC); ++i) {                     \
      float s0 = hi ? v[i] : v[i + (HC)];                                  \
      float q0 = hi ? tt[i] : tt[i + (HC)];                                \
      float s1 = __shfl_xor(s0, (M), 64);                                  \
      float q1 = __shfl_xor(q0, (M), 64);                                  \
      v[i] = (hi ? v[i + (HC)] : v[i]) + s1;                               \
      tt[i] = (hi ? tt[i + (HC)] : tt[i]) + q1;                            \
    }                                                                      \
  }

// ---------------- GIN MLP + fused BN-stats (sum/sumsq atomics) ------------
__global__ __launch_bounds__(256) void k_gin(const float* __restrict__ h,
                                             float* mh,  // msg in, h_next out
                                             const float* __restrict__ W1,
                                             const float* __restrict__ b1,
                                             const float* __restrict__ W2,
                                             const float* __restrict__ b2,
                                             float* __restrict__ stats) {
  __shared__ float sW1[D * D];
  __shared__ float sW2[D * D];
  __shared__ float sb1[D], sb2[D];
  __shared__ float lS[256], lQ[256];
  for (int i = threadIdx.x; i < D * D; i += 256) { sW1[i] = W1[i]; sW2[i] = W2[i]; }
  if (threadIdx.x < D) { sb1[threadIdx.x] = b1[threadIdx.x]; sb2[threadIdx.x] = b2[threadIdx.x]; }
  __syncthreads();
  int node = blockIdx.x * 256 + threadIdx.x;
  bool active = node < NN;
  const float4* hp = (const float4*)(h + (size_t)node * D);
  const float4* mp = (const float4*)(mh + (size_t)node * D);
  float v[D];
#pragma unroll
  for (int i = 0; i < D / 4; ++i) {
    float4 a = active ? hp[i] : make_float4(0.f, 0.f, 0.f, 0.f);
    float4 b = active ? mp[i] : make_float4(0.f, 0.f, 0.f, 0.f);
    v[4 * i + 0] = a.x + b.x;
    v[4 * i + 1] = a.y + b.y;
    v[4 * i + 2] = a.z + b.z;
    v[4 * i + 3] = a.w + b.w;
  }
  float tt[D];
#pragma unroll
  for (int j = 0; j < D; j += 4) {
    float a0 = sb1[j + 0], a1 = sb1[j + 1], a2 = sb1[j + 2], a3 = sb1[j + 3];
#pragma unroll
    for (int k = 0; k < D; ++k) {
      float vk = v[k];
      a0 = fmaf(vk, sW1[k * D + j + 0], a0);
      a1 = fmaf(vk, sW1[k * D + j + 1], a1);
      a2 = fmaf(vk, sW1[k * D + j + 2], a2);
      a3 = fmaf(vk, sW1[k * D + j + 3], a3);
    }
    tt[j + 0] = fmaxf(a0, 0.f);
    tt[j + 1] = fmaxf(a1, 0.f);
    tt[j + 2] = fmaxf(a2, 0.f);
    tt[j + 3] = fmaxf(a3, 0.f);
  }
  float4* op = (float4*)(mh + (size_t)node * D);
  float onew[4];
#pragma unroll
  for (int j = 0; j < D; j += 4) {
    float a0 = sb2[j + 0], a1 = sb2[j + 1], a2 = sb2[j + 2], a3 = sb2[j + 3];
#pragma unroll
    for (int k = 0; k < D; ++k) {
      float tk = tt[k];
      a0 = fmaf(tk, sW2[k * D + j + 0], a0);
      a1 = fmaf(tk, sW2[k * D + j + 1], a1);
      a2 = fmaf(tk, sW2[k * D + j + 2], a2);
      a3 = fmaf(tk, sW2[k * D + j + 3], a3);
    }
    onew[0] = fmaxf(a0, 0.f);
    onew[1] = fmaxf(a1, 0.f);
    onew[2] = fmaxf(a2, 0.f);
    onew[3] = fmaxf(a3, 0.f);
    if (active) {
      float4 o4 = {onew[0], onew[1], onew[2], onew[3]};
      op[j >> 2] = o4;
    }
    // stash masked outputs for the stats reduction (v is dead now)
    v[j + 0] = active ? onew[0] : 0.f;
    v[j + 1] = active ? onew[1] : 0.f;
    v[j + 2] = active ? onew[2] : 0.f;
    v[j + 3] = active ? onew[3] : 0.f;
  }
  // tt dead -> reuse for squares
#pragma unroll
  for (int i = 0; i < D; ++i) tt[i] = v[i] * v[i];
  int lane = threadIdx.x & 63;
  RSTEP(1, 32) RSTEP(2, 16) RSTEP(4, 8) RSTEP(8, 4) RSTEP(16, 2) RSTEP(32, 1)
  int f = ((lane & 1) << 5) | ((lane & 2) << 3) | ((lane & 4) << 1) |
          ((lane & 8) >> 1) | ((lane & 16) >> 3) | ((lane & 32) >> 5);
  int w = threadIdx.x >> 6;
  lS[w * 64 + f] = v[0];
  lQ[w * 64 + f] = tt[0];
  __syncthreads();
  if (threadIdx.x < 64) {
    int t = threadIdx.x;
    float S = lS[t] + lS[t + 64] + lS[t + 128] + lS[t + 192];
    float Q = lQ[t] + lQ[t + 64] + lQ[t + 128] + lQ[t + 192];
    unsafeAtomicAdd(&stats[t], S);
    unsafeAtomicAdd(&stats[D + t], Q);
  }
}

// stats[128..191] = scale, stats[192..255] = shift
__global__ void k_bnfin(float* stats, const float* __restrict__ gamma,
                        const float* __restrict__ beta) {
  int f = threadIdx.x;  // 64 threads
  float mean = stats[f] * (1.0f / NN);
  float var = stats[D + f] * (1.0f / NN) - mean * mean;
  var = fmaxf(var, 0.f);
  float sc = gamma[f] * rsqrtf(var + BN_EPS);
  stats[2 * D + f] = sc;
  stats[3 * D + f] = beta[f] - mean * sc;
}

// ---------------- fused BN-apply + per-graph mean pool ----------------
// One block per graph; float4 lanes: slot p = t&15, row r = t>>4 (16 rows).
__global__ __launch_bounds__(256) void k_bnpool(const float* __restrict__ mh,
                                                const float* __restrict__ stats,
                                                const int* __restrict__ gstart,
                                                float* __restrict__ hout,
                                                float* __restrict__ pooled,
                                                int layer) {
  __shared__ float4 sh4[256];
  int g = blockIdx.x;
  int beg = gstart[g], end = gstart[g + 1];
  int p = threadIdx.x & 15, r = threadIdx.x >> 4;
  float4 sc = ((const float4*)(stats + 2 * D))[p];
  float4 sb = ((const float4*)(stats + 3 * D))[p];
  float4 s = {0.f, 0.f, 0.f, 0.f};
  for (int n = beg + r; n < end; n += 16) {
    float4 x = ((const float4*)(mh + (size_t)n * D))[p];
    float4 o;
    o.x = fmaf(x.x, sc.x, sb.x);
    o.y = fmaf(x.y, sc.y, sb.y);
    o.z = fmaf(x.z, sc.z, sb.z);
    o.w = fmaf(x.w, sc.w, sb.w);
    ((float4*)(hout + (size_t)n * D))[p] = o;
    s.x += o.x; s.y += o.y; s.z += o.z; s.w += o.w;
  }
  sh4[threadIdx.x] = s;
  __syncthreads();
  if (threadIdx.x < 16) {
    float4 tot = {0.f, 0.f, 0.f, 0.f};
#pragma unroll
    for (int j = 0; j < 16; ++j) {
      float4 u = sh4[j * 16 + threadIdx.x];
      tot.x += u.x; tot.y += u.y; tot.z += u.z; tot.w += u.w;
    }
    int cnt = end - beg;
    float inv = 1.0f / (float)max(cnt, 1);
    float4 o = {tot.x * inv, tot.y * inv, tot.z * inv, tot.w * inv};
    ((float4*)(pooled + (size_t)g * EMBD + layer * D))[threadIdx.x] = o;
  }
}

// ---------------- projection head: one block (320 thr) per graph ----------
__global__ __launch_bounds__(EMBD) void k_proj(const float* __restrict__ pooled,
                                               const float* __restrict__ pW1,
                                               const float* __restrict__ pb1,
                                               const float* __restrict__ pW2,
                                               const float* __restrict__ pb2,
                                               float* __restrict__ out) {
  __shared__ float row[EMBD];
  __shared__ float y1[EMBD];
  int g = blockIdx.x, j = threadIdx.x;
  row[j] = pooled[(size_t)g * EMBD + j];
  __syncthreads();
  float acc = pb1[j];
#pragma unroll 4
  for (int k = 0; k < EMBD; ++k) acc = fmaf(row[k], pW1[(size_t)k * EMBD + j], acc);
  y1[j] = fmaxf(acc, 0.f);
  __syncthreads();
  acc = pb2[j];
#pragma unroll 4
  for (int k = 0; k < EMBD; ++k) acc = fmaf(y1[k], pW2[(size_t)k * EMBD + j], acc);
  out[(size_t)g * EMBD + j] = acc;
}

extern "C" void kernel_launch(void* const* d_in, const int* in_sizes, int n_in,
                              void* d_out, int out_size, void* d_ws, size_t ws_size,
                              hipStream_t stream) {
  const float* x = (const float*)d_in[0];
  const int* ei = (const int*)d_in[1];
  const float* ew = (const float*)d_in[2];
  const int* batch = (const int*)d_in[3];
  const float* W1s = (const float*)d_in[4];
  const float* b1s = (const float*)d_in[5];
  const float* W2s = (const float*)d_in[6];
  const float* b2s = (const float*)d_in[7];
  const float* gammas = (const float*)d_in[8];
  const float* betas = (const float*)d_in[9];
  const float* pW1 = (const float*)d_in[10];
  const float* pb1 = (const float*)d_in[11];
  const float* pW2 = (const float*)d_in[12];
  const float* pb2 = (const float*)d_in[13];
  const int* srcv = ei;
  const int* dstv = ei + NE;

  char* ws = (char*)d_ws;
  float* msg = (float*)ws;                               // NN*D
  float* hcur = msg + (size_t)NN * D;                    // NN*D
  float* stats = hcur + (size_t)NN * D;                  // 256
  float* pooled = stats + 256;                           // NG*EMBD
  int* gstart = (int*)(pooled + (size_t)NG * EMBD);      // NG+1
  int* row_ptr = gstart + NG + 1;                        // NN+1 (doubles as deg)
  int* cursor = row_ptr + NN + 1;                        // NN
  int2* epair = (int2*)(cursor + NN);                    // NE (8B each)
  int* bsums = (int*)(epair + NE);                       // SCAN_NB

  // ---- CSR build + graph boundaries (per call; inputs constant) ----
  hipMemsetAsync(row_ptr, 0, (NN + 1) * sizeof(int), stream);
  k_hist<<<(NE + 255) / 256, 256, 0, stream>>>(dstv, row_ptr);
  k_scan1<<<SCAN_NB, 256, 0, stream>>>(row_ptr, bsums);
  k_scan2<<<1, 512, 0, stream>>>(bsums);
  k_scan3<<<SCAN_NB, 256, 0, stream>>>(row_ptr, cursor, bsums);
  k_fill<<<(NE + 255) / 256, 256, 0, stream>>>(srcv, dstv, ew, cursor, epair);
  k_gbound<<<SCAN_NB, 256, 0, stream>>>(batch, gstart);

  const float* hin = x;
  for (int L = 0; L < NL; ++L) {
    hipMemsetAsync(stats, 0, 256 * sizeof(float), stream);
    k_gather<<<(NN * 16 + 255) / 256, 256, 0, stream>>>(hin, row_ptr, epair, msg);
    k_gin<<<SCAN_NB, 256, 0, stream>>>(hin, msg, W1s + L * D * D, b1s + L * D,
                                       W2s + L * D * D, b2s + L * D, stats);
    k_bnfin<<<1, 64, 0, stream>>>(stats, gammas + L * D, betas + L * D);
    k_bnpool<<<NG, 256, 0, stream>>>(msg, stats, gstart, hcur, pooled, L);
    hin = hcur;
  }
  k_proj<<<NG, EMBD, 0, stream>>>(pooled, pW1, pb1, pW2, pb2, (float*)d_out);
}

// Round 6
// 938.841 us; speedup vs baseline: 8.8060x; 1.2278x over previous
//
#include <hip/hip_runtime.h>

#define NN 100000
#define NE 1600000
#define D 64
#define NL 5
#define NG 1024
#define EMBD 320
#define BN_EPS 1e-5f
#define SCAN_NB ((NN + 255) / 256)  // 391
#define GIN_NB ((NN + 63) / 64)     // 1563

// ---------------- graph boundaries from sorted batch ----------------
__global__ __launch_bounds__(256) void k_gbound(const int* __restrict__ batch,
                                                int* __restrict__ gstart) {
  int i = blockIdx.x * 256 + threadIdx.x;
  if (i >= NN) return;
  int b = batch[i];
  int bp = (i == 0) ? -1 : batch[i - 1];
  for (int g = bp + 1; g <= b; ++g) gstart[g] = i;
  if (i == NN - 1) {
    for (int g = b + 1; g <= NG; ++g) gstart[g] = NN;
  }
}

// ---------------- CSR build: histogram of dst ----------------
__global__ __launch_bounds__(256) void k_hist(const int* __restrict__ dst,
                                              int* __restrict__ deg) {
  int e = blockIdx.x * 256 + threadIdx.x;
  if (e < NE) atomicAdd(&deg[dst[e]], 1);
}

// ---------------- parallel exclusive scan, 3 phases ----------------
__global__ __launch_bounds__(256) void k_scan1(const int* __restrict__ deg,
                                               int* __restrict__ bsums) {
  __shared__ int sh[256];
  int i = blockIdx.x * 256 + threadIdx.x;
  sh[threadIdx.x] = (i < NN) ? deg[i] : 0;
  __syncthreads();
  for (int off = 128; off > 0; off >>= 1) {
    if (threadIdx.x < off) sh[threadIdx.x] += sh[threadIdx.x + off];
    __syncthreads();
  }
  if (threadIdx.x == 0) bsums[blockIdx.x] = sh[0];
}

__global__ __launch_bounds__(512) void k_scan2(int* __restrict__ bsums) {
  __shared__ int sh[512];
  int t = threadIdx.x;
  int v = (t < SCAN_NB) ? bsums[t] : 0;
  sh[t] = v;
  __syncthreads();
  for (int off = 1; off < 512; off <<= 1) {
    int u = (t >= off) ? sh[t - off] : 0;
    __syncthreads();
    sh[t] += u;
    __syncthreads();
  }
  if (t < SCAN_NB) bsums[t] = sh[t] - v;  // exclusive
}

__global__ __launch_bounds__(256) void k_scan3(int* __restrict__ row_ptr,
                                               int* __restrict__ cursor,
                                               const int* __restrict__ bsums) {
  __shared__ int sh[256];
  int t = threadIdx.x;
  int i = blockIdx.x * 256 + t;
  int v = (i < NN) ? row_ptr[i] : 0;
  sh[t] = v;
  __syncthreads();
  for (int off = 1; off < 256; off <<= 1) {
    int u = (t >= off) ? sh[t - off] : 0;
    __syncthreads();
    sh[t] += u;
    __syncthreads();
  }
  int excl = sh[t] - v + bsums[blockIdx.x];
  if (i < NN) {
    row_ptr[i] = excl;
    cursor[i] = excl;
    if (i == NN - 1) row_ptr[NN] = excl + v;
  }
}

// ---------------- fill CSR: one 8B (src, w_bits) pair per edge ----------
__global__ __launch_bounds__(256) void k_fill(const int* __restrict__ src,
                                              const int* __restrict__ dst,
                                              const float* __restrict__ w,
                                              int* __restrict__ cursor,
                                              int2* __restrict__ epair) {
  int e = blockIdx.x * 256 + threadIdx.x;
  if (e >= NE) return;
  int slot = atomicAdd(&cursor[dst[e]], 1);
  int2 p;
  p.x = src[e];
  p.y = __float_as_int(w[e]);
  epair[slot] = p;
}

// ---------------- msg[n] = sum_{e in row n} w_e * h[src_e]  (16 thr/node) --
__global__ __launch_bounds__(256) void k_gather(const float* __restrict__ h,
                                                const int* __restrict__ row_ptr,
                                                const int2* __restrict__ epair,
                                                float* __restrict__ msg) {
  int t = blockIdx.x * 256 + threadIdx.x;
  int n = t >> 4, p = t & 15;
  if (n >= NN) return;
  int beg = row_ptr[n], end = row_ptr[n + 1];
  float ax = 0.f, ay = 0.f, az = 0.f, aw = 0.f;
  for (int i = beg; i < end; ++i) {
    int2 pr = epair[i];
    int s = pr.x;
    float we = __int_as_float(pr.y);
    float4 v = ((const float4*)(h + (size_t)s * D))[p];
    ax = fmaf(v.x, we, ax);
    ay = fmaf(v.y, we, ay);
    az = fmaf(v.z, we, az);
    aw = fmaf(v.w, we, aw);
  }
  float4 o = {ax, ay, az, aw};
  ((float4*)(msg + (size_t)n * D))[p] = o;
}

// ---------------- tiled GIN MLP + fused BN-stats ----------------
// Block = 256 thr, 64-node tile. Thread (nr = t>>4, fc = t&15) owns a
// 4-node x 4-feature register tile. LDS: z-tile [64][65], one W buffer
// (W1 then W2), biases, stats scratch.
__global__ __launch_bounds__(256, 4) void k_gin(const float* __restrict__ h,
                                                float* __restrict__ mh,  // msg in, h_next out
                                                const float* __restrict__ W1,
                                                const float* __restrict__ b1,
                                                const float* __restrict__ W2,
                                                const float* __restrict__ b2,
                                                float* __restrict__ stats) {
  __shared__ float zin[64 * 65];
  __shared__ float sW[64 * 64];
  __shared__ float sb[64];
  __shared__ float sSf[256], sQf[256];
  const int t = threadIdx.x;
  const int nb = blockIdx.x * 64;
  const int nr = t >> 4, fc = t & 15;

  // stage W1, b1, and z = h + msg (zero-pad inactive rows)
  for (int i = t; i < 4096; i += 256) sW[i] = W1[i];
  if (t < 64) sb[t] = b1[t];
#pragma unroll
  for (int pass = 0; pass < 4; ++pass) {
    int idx = pass * 1024 + t * 4;  // 0..4095, 16B aligned
    int r = idx >> 6, c = idx & 63;
    int n = nb + r;
    float4 val = {0.f, 0.f, 0.f, 0.f};
    if (n < NN) {
      float4 a = *(const float4*)(h + (size_t)n * D + c);
      float4 m = *(const float4*)(mh + (size_t)n * D + c);
      val.x = a.x + m.x; val.y = a.y + m.y; val.z = a.z + m.z; val.w = a.w + m.w;
    }
    *(float4*)&zin[r * 65 + c] = val;
  }
  __syncthreads();

#define GEMM_TILE(ACC)                                                        \
  {                                                                           \
    float4 bias = *(float4*)&sb[fc * 4];                                      \
    _Pragma("unroll") for (int i = 0; i < 4; ++i) ACC[i] = bias;              \
    _Pragma("unroll 4") for (int kc = 0; kc < 16; ++kc) {                     \
      float4 zv[4], wv[4];                                                    \
      _Pragma("unroll") for (int i = 0; i < 4; ++i)                           \
          zv[i] = *(float4*)&zin[(nr * 4 + i) * 65 + kc * 4];                 \
      _Pragma("unroll") for (int kk = 0; kk < 4; ++kk)                        \
          wv[kk] = *(float4*)&sW[(kc * 4 + kk) * 64 + fc * 4];                \
      _Pragma("unroll") for (int i = 0; i < 4; ++i) {                         \
        ACC[i].x = fmaf(zv[i].x, wv[0].x, ACC[i].x);                          \
        ACC[i].y = fmaf(zv[i].x, wv[0].y, ACC[i].y);                          \
        ACC[i].z = fmaf(zv[i].x, wv[0].z, ACC[i].z);                          \
        ACC[i].w = fmaf(zv[i].x, wv[0].w, ACC[i].w);                          \
        ACC[i].x = fmaf(zv[i].y, wv[1].x, ACC[i].x);                          \
        ACC[i].y = fmaf(zv[i].y, wv[1].y, ACC[i].y);                          \
        ACC[i].z = fmaf(zv[i].y, wv[1].z, ACC[i].z);                          \
        ACC[i].w = fmaf(zv[i].y, wv[1].w, ACC[i].w);                          \
        ACC[i].x = fmaf(zv[i].z, wv[2].x, ACC[i].x);                          \
        ACC[i].y = fmaf(zv[i].z, wv[2].y, ACC[i].y);                          \
        ACC[i].z = fmaf(zv[i].z, wv[2].z, ACC[i].z);                          \
        ACC[i].w = fmaf(zv[i].z, wv[2].w, ACC[i].w);                          \
        ACC[i].x = fmaf(zv[i].w, wv[3].x, ACC[i].x);                          \
        ACC[i].y = fmaf(zv[i].w, wv[3].y, ACC[i].y);                          \
        ACC[i].z = fmaf(zv[i].w, wv[3].z, ACC[i].z);                          \
        ACC[i].w = fmaf(zv[i].w, wv[3].w, ACC[i].w);                          \
      }                                                                       \
    }                                                                         \
    _Pragma("unroll") for (int i = 0; i < 4; ++i) {                           \
      ACC[i].x = fmaxf(ACC[i].x, 0.f);                                        \
      ACC[i].y = fmaxf(ACC[i].y, 0.f);                                        \
      ACC[i].z = fmaxf(ACC[i].z, 0.f);                                        \
      ACC[i].w = fmaxf(ACC[i].w, 0.f);                                        \
    }                                                                         \
  }

  float4 acc[4];
  GEMM_TILE(acc)  // GEMM1 + relu, consumed zin & sW fully
  __syncthreads();

  // overwrite zin with relu intermediate; swap in W2, b2
#pragma unroll
  for (int i = 0; i < 4; ++i) *(float4*)&zin[(nr * 4 + i) * 65 + fc * 4] = acc[i];
  for (int i = t; i < 4096; i += 256) sW[i] = W2[i];
  if (t < 64) sb[t] = b2[t];
  __syncthreads();

  float4 acc2[4];
  GEMM_TILE(acc2)  // GEMM2 + relu

  // coalesced store + masked stats partials
  float4 s4 = {0.f, 0.f, 0.f, 0.f}, q4 = {0.f, 0.f, 0.f, 0.f};
#pragma unroll
  for (int i = 0; i < 4; ++i) {
    int n = nb + nr * 4 + i;
    if (n < NN) {
      *(float4*)(mh + (size_t)n * D + fc * 4) = acc2[i];
      s4.x += acc2[i].x; s4.y += acc2[i].y; s4.z += acc2[i].z; s4.w += acc2[i].w;
      q4.x = fmaf(acc2[i].x, acc2[i].x, q4.x);
      q4.y = fmaf(acc2[i].y, acc2[i].y, q4.y);
      q4.z = fmaf(acc2[i].z, acc2[i].z, q4.z);
      q4.w = fmaf(acc2[i].w, acc2[i].w, q4.w);
    }
  }
  // reduce across the 4 node-subgroups within the wave (lane bits 4,5)
#pragma unroll
  for (int m = 16; m <= 32; m <<= 1) {
    s4.x += __shfl_xor(s4.x, m, 64); s4.y += __shfl_xor(s4.y, m, 64);
    s4.z += __shfl_xor(s4.z, m, 64); s4.w += __shfl_xor(s4.w, m, 64);
    q4.x += __shfl_xor(q4.x, m, 64); q4.y += __shfl_xor(q4.y, m, 64);
    q4.z += __shfl_xor(q4.z, m, 64); q4.w += __shfl_xor(q4.w, m, 64);
  }
  int wv_ = t >> 6;
  if ((t & 63) < 16) {
    *(float4*)&sSf[wv_ * 64 + fc * 4] = s4;
    *(float4*)&sQf[wv_ * 64 + fc * 4] = q4;
  }
  __syncthreads();
  if (t < 64) {
    float S = sSf[t] + sSf[64 + t] + sSf[128 + t] + sSf[192 + t];
    float Q = sQf[t] + sQf[64 + t] + sQf[128 + t] + sQf[192 + t];
    unsafeAtomicAdd(&stats[t], S);
    unsafeAtomicAdd(&stats[D + t], Q);
  }
#undef GEMM_TILE
}

// stats[128..191] = scale, stats[192..255] = shift
__global__ void k_bnfin(float* stats, const float* __restrict__ gamma,
                        const float* __restrict__ beta) {
  int f = threadIdx.x;  // 64 threads
  float mean = stats[f] * (1.0f / NN);
  float var = stats[D + f] * (1.0f / NN) - mean * mean;
  var = fmaxf(var, 0.f);
  float sc = gamma[f] * rsqrtf(var + BN_EPS);
  stats[2 * D + f] = sc;
  stats[3 * D + f] = beta[f] - mean * sc;
}

// ---------------- fused BN-apply + per-graph mean pool ----------------
__global__ __launch_bounds__(256) void k_bnpool(const float* __restrict__ mh,
                                                const float* __restrict__ stats,
                                                const int* __restrict__ gstart,
                                                float* __restrict__ hout,
                                                float* __restrict__ pooled,
                                                int layer) {
  __shared__ float4 sh4[256];
  int g = blockIdx.x;
  int beg = gstart[g], end = gstart[g + 1];
  int p = threadIdx.x & 15, r = threadIdx.x >> 4;
  float4 sc = ((const float4*)(stats + 2 * D))[p];
  float4 sb = ((const float4*)(stats + 3 * D))[p];
  float4 s = {0.f, 0.f, 0.f, 0.f};
  for (int n = beg + r; n < end; n += 16) {
    float4 x = ((const float4*)(mh + (size_t)n * D))[p];
    float4 o;
    o.x = fmaf(x.x, sc.x, sb.x);
    o.y = fmaf(x.y, sc.y, sb.y);
    o.z = fmaf(x.z, sc.z, sb.z);
    o.w = fmaf(x.w, sc.w, sb.w);
    ((float4*)(hout + (size_t)n * D))[p] = o;
    s.x += o.x; s.y += o.y; s.z += o.z; s.w += o.w;
  }
  sh4[threadIdx.x] = s;
  __syncthreads();
  if (threadIdx.x < 16) {
    float4 tot = {0.f, 0.f, 0.f, 0.f};
#pragma unroll
    for (int j = 0; j < 16; ++j) {
      float4 u = sh4[j * 16 + threadIdx.x];
      tot.x += u.x; tot.y += u.y; tot.z += u.z; tot.w += u.w;
    }
    int cnt = end - beg;
    float inv = 1.0f / (float)max(cnt, 1);
    float4 o = {tot.x * inv, tot.y * inv, tot.z * inv, tot.w * inv};
    ((float4*)(pooled + (size_t)g * EMBD + layer * D))[threadIdx.x] = o;
  }
}

// ---------------- projection head: one block (320 thr) per graph ----------
__global__ __launch_bounds__(EMBD) void k_proj(const float* __restrict__ pooled,
                                               const float* __restrict__ pW1,
                                               const float* __restrict__ pb1,
                                               const float* __restrict__ pW2,
                                               const float* __restrict__ pb2,
                                               float* __restrict__ out) {
  __shared__ float row[EMBD];
  __shared__ float y1[EMBD];
  int g = blockIdx.x, j = threadIdx.x;
  row[j] = pooled[(size_t)g * EMBD + j];
  __syncthreads();
  float acc = pb1[j];
#pragma unroll 4
  for (int k = 0; k < EMBD; ++k) acc = fmaf(row[k], pW1[(size_t)k * EMBD + j], acc);
  y1[j] = fmaxf(acc, 0.f);
  __syncthreads();
  acc = pb2[j];
#pragma unroll 4
  for (int k = 0; k < EMBD; ++k) acc = fmaf(y1[k], pW2[(size_t)k * EMBD + j], acc);
  out[(size_t)g * EMBD + j] = acc;
}

extern "C" void kernel_launch(void* const* d_in, const int* in_sizes, int n_in,
                              void* d_out, int out_size, void* d_ws, size_t ws_size,
                              hipStream_t stream) {
  const float* x = (const float*)d_in[0];
  const int* ei = (const int*)d_in[1];
  const float* ew = (const float*)d_in[2];
  const int* batch = (const int*)d_in[3];
  const float* W1s = (const float*)d_in[4];
  const float* b1s = (const float*)d_in[5];
  const float* W2s = (const float*)d_in[6];
  const float* b2s = (const float*)d_in[7];
  const float* gammas = (const float*)d_in[8];
  const float* betas = (const float*)d_in[9];
  const float* pW1 = (const float*)d_in[10];
  const float* pb1 = (const float*)d_in[11];
  const float* pW2 = (const float*)d_in[12];
  const float* pb2 = (const float*)d_in[13];
  const int* srcv = ei;
  const int* dstv = ei + NE;

  char* ws = (char*)d_ws;
  float* msg = (float*)ws;                               // NN*D
  float* hcur = msg + (size_t)NN * D;                    // NN*D
  float* stats = hcur + (size_t)NN * D;                  // 256
  float* pooled = stats + 256;                           // NG*EMBD
  int* gstart = (int*)(pooled + (size_t)NG * EMBD);      // NG+1
  int* row_ptr = gstart + NG + 1;                        // NN+1 (doubles as deg)
  int* cursor = row_ptr + NN + 1;                        // NN
  int2* epair = (int2*)(cursor + NN);                    // NE (8B each)
  int* bsums = (int*)(epair + NE);                       // SCAN_NB

  // ---- CSR build + graph boundaries (per call; inputs constant) ----
  hipMemsetAsync(row_ptr, 0, (NN + 1) * sizeof(int), stream);
  k_hist<<<(NE + 255) / 256, 256, 0, stream>>>(dstv, row_ptr);
  k_scan1<<<SCAN_NB, 256, 0, stream>>>(row_ptr, bsums);
  k_scan2<<<1, 512, 0, stream>>>(bsums);
  k_scan3<<<SCAN_NB, 256, 0, stream>>>(row_ptr, cursor, bsums);
  k_fill<<<(NE + 255) / 256, 256, 0, stream>>>(srcv, dstv, ew, cursor, epair);
  k_gbound<<<SCAN_NB, 256, 0, stream>>>(batch, gstart);

  const float* hin = x;
  for (int L = 0; L < NL; ++L) {
    hipMemsetAsync(stats, 0, 256 * sizeof(float), stream);
    k_gather<<<(NN * 16 + 255) / 256, 256, 0, stream>>>(hin, row_ptr, epair, msg);
    k_gin<<<GIN_NB, 256, 0, stream>>>(hin, msg, W1s + L * D * D, b1s + L * D,
                                      W2s + L * D * D, b2s + L * D, stats);
    k_bnfin<<<1, 64, 0, stream>>>(stats, gammas + L * D, betas + L * D);
    k_bnpool<<<NG, 256, 0, stream>>>(msg, stats, gstart, hcur, pooled, L);
    hin = hcur;
  }
  k_proj<<<NG, EMBD, 0, stream>>>(pooled, pW1, pb1, pW2, pb2, (float*)d_out);
}

// Round 7
// 850.406 us; speedup vs baseline: 9.7217x; 1.1040x over previous
//
#include <hip/hip_runtime.h>

#define NN 100000
#define NE 1600000
#define D 64
#define NL 5
#define NG 1024
#define EMBD 320
#define BN_EPS 1e-5f
#define SCAN_NB ((NN + 255) / 256)  // 391
#define GIN_NB ((NN + 63) / 64)     // 1563

// ---------------- graph boundaries from sorted batch ----------------
__global__ __launch_bounds__(256) void k_gbound(const int* __restrict__ batch,
                                                int* __restrict__ gstart) {
  int i = blockIdx.x * 256 + threadIdx.x;
  if (i >= NN) return;
  int b = batch[i];
  int bp = (i == 0) ? -1 : batch[i - 1];
  for (int g = bp + 1; g <= b; ++g) gstart[g] = i;
  if (i == NN - 1) {
    for (int g = b + 1; g <= NG; ++g) gstart[g] = NN;
  }
}

// ---------------- CSR build: histogram of dst ----------------
__global__ __launch_bounds__(256) void k_hist(const int* __restrict__ dst,
                                              int* __restrict__ deg) {
  int e = blockIdx.x * 256 + threadIdx.x;
  if (e < NE) atomicAdd(&deg[dst[e]], 1);
}

// ---------------- parallel exclusive scan, 3 phases ----------------
__global__ __launch_bounds__(256) void k_scan1(const int* __restrict__ deg,
                                               int* __restrict__ bsums) {
  __shared__ int sh[256];
  int i = blockIdx.x * 256 + threadIdx.x;
  sh[threadIdx.x] = (i < NN) ? deg[i] : 0;
  __syncthreads();
  for (int off = 128; off > 0; off >>= 1) {
    if (threadIdx.x < off) sh[threadIdx.x] += sh[threadIdx.x + off];
    __syncthreads();
  }
  if (threadIdx.x == 0) bsums[blockIdx.x] = sh[0];
}

__global__ __launch_bounds__(512) void k_scan2(int* __restrict__ bsums) {
  __shared__ int sh[512];
  int t = threadIdx.x;
  int v = (t < SCAN_NB) ? bsums[t] : 0;
  sh[t] = v;
  __syncthreads();
  for (int off = 1; off < 512; off <<= 1) {
    int u = (t >= off) ? sh[t - off] : 0;
    __syncthreads();
    sh[t] += u;
    __syncthreads();
  }
  if (t < SCAN_NB) bsums[t] = sh[t] - v;  // exclusive
}

__global__ __launch_bounds__(256) void k_scan3(int* __restrict__ row_ptr,
                                               int* __restrict__ cursor,
                                               const int* __restrict__ bsums) {
  __shared__ int sh[256];
  int t = threadIdx.x;
  int i = blockIdx.x * 256 + t;
  int v = (i < NN) ? row_ptr[i] : 0;
  sh[t] = v;
  __syncthreads();
  for (int off = 1; off < 256; off <<= 1) {
    int u = (t >= off) ? sh[t - off] : 0;
    __syncthreads();
    sh[t] += u;
    __syncthreads();
  }
  int excl = sh[t] - v + bsums[blockIdx.x];
  if (i < NN) {
    row_ptr[i] = excl;
    cursor[i] = excl;
    if (i == NN - 1) row_ptr[NN] = excl + v;
  }
}

// ---------------- fill CSR: one 8B (src, w_bits) pair per edge ----------
__global__ __launch_bounds__(256) void k_fill(const int* __restrict__ src,
                                              const int* __restrict__ dst,
                                              const float* __restrict__ w,
                                              int* __restrict__ cursor,
                                              int2* __restrict__ epair) {
  int e = blockIdx.x * 256 + threadIdx.x;
  if (e >= NE) return;
  int slot = atomicAdd(&cursor[dst[e]], 1);
  int2 p;
  p.x = src[e];
  p.y = __float_as_int(w[e]);
  epair[slot] = p;
}

// ---------------- fused gather + GIN MLP + BN-stats ----------------
// Block = 256 thr, 64-node tile.
// Staging: 4 thr/node accumulate z = h[n] + sum_e w*h[src] into LDS.
// GEMM: thread (nr=t>>4, fc=t&15) owns 4-node x 4-feature register tile.
#define FMA4(A, V) \
  A.x = fmaf(V.x, we, A.x); A.y = fmaf(V.y, we, A.y); \
  A.z = fmaf(V.z, we, A.z); A.w = fmaf(V.w, we, A.w);

__global__ __launch_bounds__(256, 4) void k_gin(const float* __restrict__ h,
                                                float* __restrict__ gout,
                                                const int* __restrict__ row_ptr,
                                                const int2* __restrict__ epair,
                                                const float* __restrict__ W1,
                                                const float* __restrict__ b1,
                                                const float* __restrict__ W2,
                                                const float* __restrict__ b2,
                                                float* __restrict__ statsL) {
  __shared__ float zin[64 * 65];
  __shared__ float sW[64 * 64];
  __shared__ float sb[64];
  __shared__ float sSf[256], sQf[256];
  const int t = threadIdx.x;
  const int nb = blockIdx.x * 64;
  const int nr = t >> 4, fc = t & 15;

  // stage W1, b1
  for (int i = t; i < 4096; i += 256) sW[i] = W1[i];
  if (t < 64) sb[t] = b1[t];

  // staging: gather + self term -> zin
  {
    const int nl = t >> 2;        // 0..63 local node
    const int q = t & 3;          // quarter of the row (4 float4 slots)
    const int n = nb + nl;
    float4 a0 = {0.f, 0.f, 0.f, 0.f}, a1 = a0, a2 = a0, a3 = a0;
    if (n < NN) {
      const int beg = row_ptr[n], end = row_ptr[n + 1];
      const float4* own = (const float4*)(h + (size_t)n * D) + q * 4;
      for (int i = beg; i < end; ++i) {
        const int2 pr = epair[i];
        const float we = __int_as_float(pr.y);
        const float4* hp = (const float4*)(h + (size_t)pr.x * D) + q * 4;
        float4 v0 = hp[0], v1 = hp[1], v2 = hp[2], v3 = hp[3];
        FMA4(a0, v0) FMA4(a1, v1) FMA4(a2, v2) FMA4(a3, v3)
      }
      float4 o0 = own[0], o1 = own[1], o2 = own[2], o3 = own[3];
      a0.x += o0.x; a0.y += o0.y; a0.z += o0.z; a0.w += o0.w;
      a1.x += o1.x; a1.y += o1.y; a1.z += o1.z; a1.w += o1.w;
      a2.x += o2.x; a2.y += o2.y; a2.z += o2.z; a2.w += o2.w;
      a3.x += o3.x; a3.y += o3.y; a3.z += o3.z; a3.w += o3.w;
    }
    float* zr = &zin[nl * 65 + q * 16];
    *(float4*)(zr + 0) = a0;
    *(float4*)(zr + 4) = a1;
    *(float4*)(zr + 8) = a2;
    *(float4*)(zr + 12) = a3;
  }
  __syncthreads();

#define GEMM_TILE(ACC)                                                        \
  {                                                                           \
    float4 bias = *(float4*)&sb[fc * 4];                                      \
    _Pragma("unroll") for (int i = 0; i < 4; ++i) ACC[i] = bias;              \
    _Pragma("unroll 4") for (int kc = 0; kc < 16; ++kc) {                     \
      float4 zv[4], wv[4];                                                    \
      _Pragma("unroll") for (int i = 0; i < 4; ++i)                           \
          zv[i] = *(float4*)&zin[(nr * 4 + i) * 65 + kc * 4];                 \
      _Pragma("unroll") for (int kk = 0; kk < 4; ++kk)                        \
          wv[kk] = *(float4*)&sW[(kc * 4 + kk) * 64 + fc * 4];                \
      _Pragma("unroll") for (int i = 0; i < 4; ++i) {                         \
        ACC[i].x = fmaf(zv[i].x, wv[0].x, ACC[i].x);                          \
        ACC[i].y = fmaf(zv[i].x, wv[0].y, ACC[i].y);                          \
        ACC[i].z = fmaf(zv[i].x, wv[0].z, ACC[i].z);                          \
        ACC[i].w = fmaf(zv[i].x, wv[0].w, ACC[i].w);                          \
        ACC[i].x = fmaf(zv[i].y, wv[1].x, ACC[i].x);                          \
        ACC[i].y = fmaf(zv[i].y, wv[1].y, ACC[i].y);                          \
        ACC[i].z = fmaf(zv[i].y, wv[1].z, ACC[i].z);                          \
        ACC[i].w = fmaf(zv[i].y, wv[1].w, ACC[i].w);                          \
        ACC[i].x = fmaf(zv[i].z, wv[2].x, ACC[i].x);                          \
        ACC[i].y = fmaf(zv[i].z, wv[2].y, ACC[i].y);                          \
        ACC[i].z = fmaf(zv[i].z, wv[2].z, ACC[i].z);                          \
        ACC[i].w = fmaf(zv[i].z, wv[2].w, ACC[i].w);                          \
        ACC[i].x = fmaf(zv[i].w, wv[3].x, ACC[i].x);                          \
        ACC[i].y = fmaf(zv[i].w, wv[3].y, ACC[i].y);                          \
        ACC[i].z = fmaf(zv[i].w, wv[3].z, ACC[i].z);                          \
        ACC[i].w = fmaf(zv[i].w, wv[3].w, ACC[i].w);                          \
      }                                                                       \
    }                                                                         \
    _Pragma("unroll") for (int i = 0; i < 4; ++i) {                           \
      ACC[i].x = fmaxf(ACC[i].x, 0.f);                                        \
      ACC[i].y = fmaxf(ACC[i].y, 0.f);                                        \
      ACC[i].z = fmaxf(ACC[i].z, 0.f);                                        \
      ACC[i].w = fmaxf(ACC[i].w, 0.f);                                        \
    }                                                                         \
  }

  float4 acc[4];
  GEMM_TILE(acc)  // GEMM1 + relu
  __syncthreads();

  // overwrite zin with relu intermediate; swap in W2, b2
#pragma unroll
  for (int i = 0; i < 4; ++i) *(float4*)&zin[(nr * 4 + i) * 65 + fc * 4] = acc[i];
  for (int i = t; i < 4096; i += 256) sW[i] = W2[i];
  if (t < 64) sb[t] = b2[t];
  __syncthreads();

  float4 acc2[4];
  GEMM_TILE(acc2)  // GEMM2 + relu

  // coalesced store + masked stats partials
  float4 s4 = {0.f, 0.f, 0.f, 0.f}, q4 = {0.f, 0.f, 0.f, 0.f};
#pragma unroll
  for (int i = 0; i < 4; ++i) {
    int n = nb + nr * 4 + i;
    if (n < NN) {
      *(float4*)(gout + (size_t)n * D + fc * 4) = acc2[i];
      s4.x += acc2[i].x; s4.y += acc2[i].y; s4.z += acc2[i].z; s4.w += acc2[i].w;
      q4.x = fmaf(acc2[i].x, acc2[i].x, q4.x);
      q4.y = fmaf(acc2[i].y, acc2[i].y, q4.y);
      q4.z = fmaf(acc2[i].z, acc2[i].z, q4.z);
      q4.w = fmaf(acc2[i].w, acc2[i].w, q4.w);
    }
  }
#pragma unroll
  for (int m = 16; m <= 32; m <<= 1) {
    s4.x += __shfl_xor(s4.x, m, 64); s4.y += __shfl_xor(s4.y, m, 64);
    s4.z += __shfl_xor(s4.z, m, 64); s4.w += __shfl_xor(s4.w, m, 64);
    q4.x += __shfl_xor(q4.x, m, 64); q4.y += __shfl_xor(q4.y, m, 64);
    q4.z += __shfl_xor(q4.z, m, 64); q4.w += __shfl_xor(q4.w, m, 64);
  }
  int wv_ = t >> 6;
  if ((t & 63) < 16) {
    *(float4*)&sSf[wv_ * 64 + fc * 4] = s4;
    *(float4*)&sQf[wv_ * 64 + fc * 4] = q4;
  }
  __syncthreads();
  if (t < 64) {
    float S = sSf[t] + sSf[64 + t] + sSf[128 + t] + sSf[192 + t];
    float Q = sQf[t] + sQf[64 + t] + sQf[128 + t] + sQf[192 + t];
    unsafeAtomicAdd(&statsL[t], S);
    unsafeAtomicAdd(&statsL[64 + t], Q);
  }
#undef GEMM_TILE
}

// ---------------- fused BN-finalize + BN-apply + per-graph mean pool ------
__global__ __launch_bounds__(256) void k_bnpool(const float* __restrict__ mh,
                                                const float* __restrict__ statsL,
                                                const float* __restrict__ gamma,
                                                const float* __restrict__ beta,
                                                const int* __restrict__ gstart,
                                                float* __restrict__ hout,
                                                float* __restrict__ pooled,
                                                int layer) {
  __shared__ float4 sh4[256];
  int g = blockIdx.x;
  int beg = gstart[g], end = gstart[g + 1];
  int p = threadIdx.x & 15, r = threadIdx.x >> 4;
  float4 S = ((const float4*)statsL)[p];
  float4 Q = ((const float4*)(statsL + 64))[p];
  float4 gm = ((const float4*)gamma)[p];
  float4 bt = ((const float4*)beta)[p];
  float4 sc, sb;
  {
    float m, v;
    m = S.x * (1.f / NN); v = fmaxf(Q.x * (1.f / NN) - m * m, 0.f);
    sc.x = gm.x * rsqrtf(v + BN_EPS); sb.x = bt.x - m * sc.x;
    m = S.y * (1.f / NN); v = fmaxf(Q.y * (1.f / NN) - m * m, 0.f);
    sc.y = gm.y * rsqrtf(v + BN_EPS); sb.y = bt.y - m * sc.y;
    m = S.z * (1.f / NN); v = fmaxf(Q.z * (1.f / NN) - m * m, 0.f);
    sc.z = gm.z * rsqrtf(v + BN_EPS); sb.z = bt.z - m * sc.z;
    m = S.w * (1.f / NN); v = fmaxf(Q.w * (1.f / NN) - m * m, 0.f);
    sc.w = gm.w * rsqrtf(v + BN_EPS); sb.w = bt.w - m * sc.w;
  }
  float4 s = {0.f, 0.f, 0.f, 0.f};
  for (int n = beg + r; n < end; n += 16) {
    float4 x = ((const float4*)(mh + (size_t)n * D))[p];
    float4 o;
    o.x = fmaf(x.x, sc.x, sb.x);
    o.y = fmaf(x.y, sc.y, sb.y);
    o.z = fmaf(x.z, sc.z, sb.z);
    o.w = fmaf(x.w, sc.w, sb.w);
    ((float4*)(hout + (size_t)n * D))[p] = o;
    s.x += o.x; s.y += o.y; s.z += o.z; s.w += o.w;
  }
  sh4[threadIdx.x] = s;
  __syncthreads();
  if (threadIdx.x < 16) {
    float4 tot = {0.f, 0.f, 0.f, 0.f};
#pragma unroll
    for (int j = 0; j < 16; ++j) {
      float4 u = sh4[j * 16 + threadIdx.x];
      tot.x += u.x; tot.y += u.y; tot.z += u.z; tot.w += u.w;
    }
    int cnt = end - beg;
    float inv = 1.0f / (float)max(cnt, 1);
    float4 o = {tot.x * inv, tot.y * inv, tot.z * inv, tot.w * inv};
    ((float4*)(pooled + (size_t)g * EMBD + layer * D))[threadIdx.x] = o;
  }
}

// ---------------- projection head: one block (320 thr) per graph ----------
__global__ __launch_bounds__(EMBD) void k_proj(const float* __restrict__ pooled,
                                               const float* __restrict__ pW1,
                                               const float* __restrict__ pb1,
                                               const float* __restrict__ pW2,
                                               const float* __restrict__ pb2,
                                               float* __restrict__ out) {
  __shared__ float row[EMBD];
  __shared__ float y1[EMBD];
  int g = blockIdx.x, j = threadIdx.x;
  row[j] = pooled[(size_t)g * EMBD + j];
  __syncthreads();
  float acc = pb1[j];
#pragma unroll 4
  for (int k = 0; k < EMBD; ++k) acc = fmaf(row[k], pW1[(size_t)k * EMBD + j], acc);
  y1[j] = fmaxf(acc, 0.f);
  __syncthreads();
  acc = pb2[j];
#pragma unroll 4
  for (int k = 0; k < EMBD; ++k) acc = fmaf(y1[k], pW2[(size_t)k * EMBD + j], acc);
  out[(size_t)g * EMBD + j] = acc;
}

extern "C" void kernel_launch(void* const* d_in, const int* in_sizes, int n_in,
                              void* d_out, int out_size, void* d_ws, size_t ws_size,
                              hipStream_t stream) {
  const float* x = (const float*)d_in[0];
  const int* ei = (const int*)d_in[1];
  const float* ew = (const float*)d_in[2];
  const int* batch = (const int*)d_in[3];
  const float* W1s = (const float*)d_in[4];
  const float* b1s = (const float*)d_in[5];
  const float* W2s = (const float*)d_in[6];
  const float* b2s = (const float*)d_in[7];
  const float* gammas = (const float*)d_in[8];
  const float* betas = (const float*)d_in[9];
  const float* pW1 = (const float*)d_in[10];
  const float* pb1 = (const float*)d_in[11];
  const float* pW2 = (const float*)d_in[12];
  const float* pb2 = (const float*)d_in[13];
  const int* srcv = ei;
  const int* dstv = ei + NE;

  char* ws = (char*)d_ws;
  float* gout = (float*)ws;                              // NN*D (GIN output)
  float* hcur = gout + (size_t)NN * D;                   // NN*D
  float* stats = hcur + (size_t)NN * D;                  // NL*128
  float* pooled = stats + NL * 128;                      // NG*EMBD
  int* gstart = (int*)(pooled + (size_t)NG * EMBD);      // NG+1
  int* row_ptr = gstart + NG + 1;                        // NN+1 (doubles as deg)
  int* cursor = row_ptr + NN + 1;                        // NN
  int2* epair = (int2*)(cursor + NN);                    // NE (8B each)
  int* bsums = (int*)(epair + NE);                       // SCAN_NB

  // ---- CSR build + graph boundaries + stats zero (per call) ----
  hipMemsetAsync(row_ptr, 0, (NN + 1) * sizeof(int), stream);
  hipMemsetAsync(stats, 0, NL * 128 * sizeof(float), stream);
  k_hist<<<(NE + 255) / 256, 256, 0, stream>>>(dstv, row_ptr);
  k_scan1<<<SCAN_NB, 256, 0, stream>>>(row_ptr, bsums);
  k_scan2<<<1, 512, 0, stream>>>(bsums);
  k_scan3<<<SCAN_NB, 256, 0, stream>>>(row_ptr, cursor, bsums);
  k_fill<<<(NE + 255) / 256, 256, 0, stream>>>(srcv, dstv, ew, cursor, epair);
  k_gbound<<<SCAN_NB, 256, 0, stream>>>(batch, gstart);

  const float* hin = x;
  for (int L = 0; L < NL; ++L) {
    k_gin<<<GIN_NB, 256, 0, stream>>>(hin, gout, row_ptr, epair,
                                      W1s + L * D * D, b1s + L * D,
                                      W2s + L * D * D, b2s + L * D,
                                      stats + L * 128);
    k_bnpool<<<NG, 256, 0, stream>>>(gout, stats + L * 128, gammas + L * D,
                                     betas + L * D, gstart, hcur, pooled, L);
    hin = hcur;
  }
  k_proj<<<NG, EMBD, 0, stream>>>(pooled, pW1, pb1, pW2, pb2, (float*)d_out);
}